// Round 6
// baseline (944.285 us; speedup 1.0000x reference)
//
#include <hip/hip_runtime.h>
#include <hip/hip_fp16.h>
#include <hip/hip_cooperative_groups.h>

namespace cg = cooperative_groups;

#define N_NODES 50000
#define N_EDGES 800000
#define BN_EPS 1e-5f

#define NBUCK 196        // ceil(50000/256) buckets of 256 nodes
#define PART_CAP 6016    // per-bucket capacity; mean 4082, sd 64 -> 30 sigma margin
#define PB 196           // partition jobs (ceil(800000/4096))
#define GB 782           // gemm0 jobs (ceil(50000/64), 64-row tiles)
#define GATHER_JOBS ((N_NODES + 31) / 32)   // 1563
#define OUT_JOBS ((N_NODES + 49) / 50)      // 1000
#define SMEM_BYTES 25088  // max over phases: gather 64-out = 8704(zs)+16384(Ws)

// exclusive 256-thread scan in LDS; s[] is scratch (256 ints). Returns exclusive prefix.
__device__ __forceinline__ int lds_scan256_excl(int* s, int t, int v) {
    s[t] = v;
    __syncthreads();
    for (int off = 1; off < 256; off <<= 1) {
        int x = (t >= off) ? s[t - off] : 0;
        __syncthreads();
        s[t] += x;
        __syncthreads();
    }
    return s[t] - v;
}

// phase of a source node id (4 ranges of 12500); exact floor(s/12500) for s<50000
__device__ __forceinline__ unsigned src_phase(unsigned s) {
    return (s * 42950u) >> 29;
}

// ---------------- GEMM0 job: Hs[r,64] = X[r,128] @ (W0 .* bn0scale[c]) ----------------
// 64-row tile; 256 threads = 16x16, each 4x4. (proven shape; 8x8/256-row variant
// collapsed parallelism: 76us @ 8% VALUBusy -- do not revisit.)
__device__ __forceinline__ void gemm0_job(int bid, const float* __restrict__ X,
                                          const float* __restrict__ W,
                                          const float* __restrict__ gamma,
                                          const float* __restrict__ var,
                                          float* Hs, int n, float* lds) {
    constexpr int K = 128, M = 64, KC = 32;
    float* Xs = lds;                     // 64 x 36
    float* Ws = lds + 64 * 36;           // 32 x 64
    float* bns = lds + 64 * 36 + 32 * 64; // 64 bn scales
    int tid = threadIdx.x;
    int tx = tid & 15, ty = tid >> 4;
    int row0 = bid * 64;
    if (tid < M) bns[tid] = gamma[tid] * rsqrtf(var[tid] + BN_EPS);
    __syncthreads();
    float acc[4][4] = {};
    for (int k0 = 0; k0 < K; k0 += KC) {
#pragma unroll
        for (int it = 0; it < 2; ++it) {
            int fi = tid + it * 256;            // 512 float4s
            int r = fi >> 3, q = fi & 7;
            int row = row0 + r;
            float4 v = make_float4(0.f, 0.f, 0.f, 0.f);
            if (row < n) v = *(const float4*)&X[(size_t)row * K + k0 + q * 4];
            *(float4*)&Xs[r * 36 + q * 4] = v;
        }
#pragma unroll
        for (int it = 0; it < 2; ++it) {
            int fi = tid + it * 256;            // 512 float4s
            int kk = fi >> 4, cw = (fi & 15) * 4;
            float4 w = *(const float4*)&W[(size_t)(k0 + kk) * M + cw];
            w.x *= bns[cw]; w.y *= bns[cw + 1]; w.z *= bns[cw + 2]; w.w *= bns[cw + 3];
            *(float4*)&Ws[kk * M + cw] = w;
        }
        __syncthreads();
#pragma unroll 8
        for (int kk = 0; kk < KC; ++kk) {
            float4 bv = *(float4*)&Ws[kk * M + tx * 4];
#pragma unroll
            for (int j = 0; j < 4; ++j) {
                float a = Xs[(ty * 4 + j) * 36 + kk];
                acc[j][0] += a * bv.x;
                acc[j][1] += a * bv.y;
                acc[j][2] += a * bv.z;
                acc[j][3] += a * bv.w;
            }
        }
        __syncthreads();
    }
#pragma unroll
    for (int j = 0; j < 4; ++j) {
        int r = row0 + ty * 4 + j;
        if (r < n) {
            float4 v = make_float4(acc[j][0], acc[j][1], acc[j][2], acc[j][3]);
            *(float4*)&Hs[(size_t)r * M + tx * 4] = v;
        }
    }
}

// ---------------- partition job: bin 4096 edges by dst>>8 ----------------
__device__ __forceinline__ void partition_job(int pj, const int* __restrict__ src,
                                              const int* __restrict__ dst,
                                              int* __restrict__ gcur,
                                              unsigned int* __restrict__ part,
                                              int nE, int* lds) {
    int* lcnt  = lds;          // 196
    int* gbase = lds + 256;    // 196
    int t = threadIdx.x;
    int base = pj * 4096;
    for (int i = t; i < NBUCK; i += 256) lcnt[i] = 0;
    __syncthreads();
    unsigned int val[16], pk[16];
#pragma unroll
    for (int i = 0; i < 16; ++i) {
        int e = base + i * 256 + t;
        if (e < nE) {
            unsigned s = (unsigned)src[e], d = (unsigned)dst[e];
            unsigned b = d >> 8;
            int r = atomicAdd(&lcnt[b], 1);
            val[i] = s | ((d & 255u) << 16);
            pk[i] = b | ((unsigned)r << 8);
        } else pk[i] = 0xffffffffu;
    }
    __syncthreads();
    for (int i = t; i < NBUCK; i += 256) gbase[i] = atomicAdd(&gcur[i], lcnt[i]);
    __syncthreads();
#pragma unroll
    for (int i = 0; i < 16; ++i) {
        if (pk[i] != 0xffffffffu) {
            unsigned b = pk[i] & 255u;
            unsigned p = (unsigned)gbase[b] + (pk[i] >> 8);
            if (p < PART_CAP) part[b * PART_CAP + p] = val[i];
        }
    }
}

// ---------------- build job: per-bucket CSR (4-phase src-grouped) + dinv + fp16 table ----
// (counting sort, NOT insertion sort: r3 measured +50us serial/divergent for the latter)
__device__ __forceinline__ void build_job(int b, const unsigned int* __restrict__ part,
                                          const int* __restrict__ gcur,
                                          int* __restrict__ rowptr, float* __restrict__ dinv,
                                          unsigned short* __restrict__ csr,
                                          const float* Hs, __half* __restrict__ Hh,
                                          int n, char* smem) {
    int* sc   = (int*)smem;               // 256
    int* ns   = sc + 256;                 // 256
    int* nc4  = ns + 256;                 // 1024
    int* cur4 = nc4 + 1024;               // 1024
    float* sdinv = (float*)(cur4 + 1024); // 256
    int* sh   = (int*)(sdinv + 256);      // 2  (sh[0]=off, sh[1]=ec)
    unsigned short* csr_lds = (unsigned short*)(sh + 2);  // 6016
    int t = threadIdx.x;
    int v = (t < NBUCK) ? gcur[t] : 0;
    int ex = lds_scan256_excl(sc, t, v);
    if (t == b) { sh[0] = ex; sh[1] = v; }
    nc4[t * 4 + 0] = 0; nc4[t * 4 + 1] = 0; nc4[t * 4 + 2] = 0; nc4[t * 4 + 3] = 0;
    __syncthreads();
    int off = sh[0];
    int ec = sh[1] < PART_CAP ? sh[1] : PART_CAP;
    const unsigned int* pb = part + (size_t)b * PART_CAP;
    for (int i = t; i < ec; i += 256) {
        unsigned w = pb[i];
        atomicAdd(&nc4[((w >> 16) & 255u) * 4 + src_phase(w & 0xffffu)], 1);
    }
    __syncthreads();
    int c0 = nc4[t * 4 + 0], c1 = nc4[t * 4 + 1], c2 = nc4[t * 4 + 2], c3 = nc4[t * 4 + 3];
    int c = c0 + c1 + c2 + c3;
    int nx = lds_scan256_excl(ns, t, c);
    cur4[t * 4 + 0] = nx;
    cur4[t * 4 + 1] = nx + c0;
    cur4[t * 4 + 2] = nx + c0 + c1;
    cur4[t * 4 + 3] = nx + c0 + c1 + c2;
    float dv = rsqrtf((float)c + 1.0f);   // +1 = self loop
    sdinv[t] = dv;
    int node = b * 256 + t;
    if (node < n) {
        rowptr[node] = off + nx;
        dinv[node] = dv;
    }
    if (b == NBUCK - 1 && t == 0) rowptr[n] = off + ec;
    __syncthreads();
    for (int i = t; i < ec; i += 256) {
        unsigned w = pb[i];
        unsigned nd = (w >> 16) & 255u;
        unsigned s = w & 0xffffu;
        int p = atomicAdd(&cur4[nd * 4 + src_phase(s)], 1);
        csr_lds[p] = (unsigned short)s;
    }
    __syncthreads();
    for (int i = t; i < ec; i += 256) csr[off + i] = csr_lds[i];
    // convert this bucket's Hs rows to fp16 with dinv prefold
    const float4* H4 = (const float4*)(Hs + (size_t)b * 256 * 64);
    for (int i = t; i < 4096; i += 256) {
        int nd = i >> 4;
        int nn = b * 256 + nd;
        if (nn < n) {
            float s = sdinv[nd];
            float4 x = H4[i];
            union { uint2 u; __half2 h[2]; } U;
            U.h[0] = __floats2half2_rn(x.x * s, x.y * s);
            U.h[1] = __floats2half2_rn(x.z * s, x.w * s);
            *(uint2*)&Hh[(size_t)nn * 64 + (i & 15) * 4] = U.u;
        }
    }
}

// ---------------- gather (fp16 table, BN+ReLU) + next-layer GEMM; 32 nodes x 8 lanes ----
template <int MOUT, bool FOLD_NEXT>
__device__ __forceinline__ void gather_job(int job, const __half* Hh,
                                           const int* __restrict__ rowptr,
                                           const unsigned short* __restrict__ csr,
                                           const float* __restrict__ dinv,
                                           const float* __restrict__ bb,
                                           const float* __restrict__ gamma,
                                           const float* __restrict__ beta,
                                           const float* __restrict__ mean,
                                           const float* __restrict__ var,
                                           const float* __restrict__ Wn,
                                           const float* __restrict__ gn,
                                           const float* __restrict__ vn,
                                           __half* Hout, int n, char* smem) {
    float* zs = (float*)smem;       // 32 x 68 (pad 68: conflict-free z reads)
    float* Ws = zs + 32 * 68;       // 64 x MOUT
    int t = threadIdx.x;
    int nd = t >> 3, l = t & 7;
    int d = job * 32 + nd;
    int c8 = l * 8;
    for (int i = t; i < 64 * MOUT; i += 256) {
        float w = Wn[i];
        if (FOLD_NEXT) { int c = i % MOUT; w *= gn[c] * rsqrtf(vn[c] + BN_EPS); }
        Ws[i] = w;
    }
    float acc[8] = {};
    float di = 0.f;
    int beg = 0, end = 0;
    if (d < n) {
        beg = rowptr[d]; end = rowptr[d + 1];
        di = dinv[d];
        union { uint4 u; __half2 h[4]; } S;
        S.u = *(const uint4*)&Hh[(size_t)d * 64 + c8];   // self loop (prescaled)
#pragma unroll
        for (int p = 0; p < 4; ++p) {
            float2 f = __half22float2(S.h[p]);
            acc[2 * p] += f.x; acc[2 * p + 1] += f.y;
        }
    }
    int e = beg;
    int head = (beg + 7) & ~7;             // align for uint4 index loads
    if (head > end) head = end;
    for (; e < head; ++e) {
        int s = csr[e];
        union { uint4 u; __half2 h[4]; } V;
        V.u = *(const uint4*)&Hh[(size_t)s * 64 + c8];
#pragma unroll
        for (int p = 0; p < 4; ++p) {
            float2 f = __half22float2(V.h[p]);
            acc[2 * p] += f.x; acc[2 * p + 1] += f.y;
        }
    }
    for (; e + 8 <= end; e += 8) {
        uint4 iv = *(const uint4*)&csr[e];   // 8 indices in one 16B load
        int sidx[8];
        sidx[0] = iv.x & 0xffff; sidx[1] = iv.x >> 16;
        sidx[2] = iv.y & 0xffff; sidx[3] = iv.y >> 16;
        sidx[4] = iv.z & 0xffff; sidx[5] = iv.z >> 16;
        sidx[6] = iv.w & 0xffff; sidx[7] = iv.w >> 16;
        uint4 vv[8];
#pragma unroll
        for (int q = 0; q < 8; ++q)
            vv[q] = *(const uint4*)&Hh[(size_t)sidx[q] * 64 + c8];
#pragma unroll
        for (int q = 0; q < 8; ++q) {
            union { uint4 u; __half2 h[4]; } V; V.u = vv[q];
#pragma unroll
            for (int p = 0; p < 4; ++p) {
                float2 f = __half22float2(V.h[p]);
                acc[2 * p] += f.x; acc[2 * p + 1] += f.y;
            }
        }
    }
    for (; e < end; ++e) {
        int s = csr[e];
        union { uint4 u; __half2 h[4]; } V;
        V.u = *(const uint4*)&Hh[(size_t)s * 64 + c8];
#pragma unroll
        for (int p = 0; p < 4; ++p) {
            float2 f = __half22float2(V.h[p]);
            acc[2 * p] += f.x; acc[2 * p + 1] += f.y;
        }
    }
    if (d < n) {
#pragma unroll
        for (int q = 0; q < 8; ++q) {
            int cc = c8 + q;
            float s0 = gamma[cc] * rsqrtf(var[cc] + BN_EPS);
            float bias = (bb[cc] - mean[cc]) * s0 + beta[cc];
            zs[nd * 68 + cc] = fmaxf(acc[q] * di + bias, 0.0f);
        }
    }
    __syncthreads();
    if (c8 < MOUT && d < n) {
        float o[8] = {};
        for (int k0 = 0; k0 < 64; k0 += 4) {
            float4 zq = *(const float4*)&zs[nd * 68 + k0];
#pragma unroll
            for (int j = 0; j < 4; ++j) {
                float zk = (&zq.x)[j];
                float4 w0 = *(const float4*)&Ws[(k0 + j) * MOUT + c8];
                float4 w1 = *(const float4*)&Ws[(k0 + j) * MOUT + c8 + 4];
                o[0] += zk * w0.x; o[1] += zk * w0.y; o[2] += zk * w0.z; o[3] += zk * w0.w;
                o[4] += zk * w1.x; o[5] += zk * w1.y; o[6] += zk * w1.z; o[7] += zk * w1.w;
            }
        }
        union { uint4 u; __half2 h[4]; } O;
#pragma unroll
        for (int p = 0; p < 4; ++p)
            O.h[p] = __floats2half2_rn(o[2 * p] * di, o[2 * p + 1] * di);
        *(uint4*)&Hout[(size_t)d * MOUT + c8] = O.u;
    }
}

// ---------------- final gather over fp16 40-ch rows; fp32 out; 50 nodes x 5 lanes ----
__device__ __forceinline__ void gather_out_job(int job, const __half* t3,
                                               const int* __restrict__ rowptr,
                                               const unsigned short* __restrict__ csr,
                                               const float* __restrict__ dinv,
                                               const float* __restrict__ bias,
                                               float* __restrict__ out, int n) {
    int t = threadIdx.x;
    if (t >= 250) return;
    int nd = t / 5, l = t % 5;
    int d = job * 50 + nd;
    if (d >= n) return;
    int c8 = l * 8;
    int beg = rowptr[d], end = rowptr[d + 1];
    float di = dinv[d];
    float acc[8];
    {
        union { uint4 u; __half2 h[4]; } S;
        S.u = *(const uint4*)&t3[(size_t)d * 40 + c8];
#pragma unroll
        for (int p = 0; p < 4; ++p) {
            float2 f = __half22float2(S.h[p]);
            acc[2 * p] = f.x; acc[2 * p + 1] = f.y;
        }
    }
    int e = beg;
    int head = (beg + 7) & ~7;
    if (head > end) head = end;
    for (; e < head; ++e) {
        int s = csr[e];
        union { uint4 u; __half2 h[4]; } V;
        V.u = *(const uint4*)&t3[(size_t)s * 40 + c8];
#pragma unroll
        for (int p = 0; p < 4; ++p) {
            float2 f = __half22float2(V.h[p]);
            acc[2 * p] += f.x; acc[2 * p + 1] += f.y;
        }
    }
    for (; e + 8 <= end; e += 8) {
        uint4 iv = *(const uint4*)&csr[e];
        int sidx[8];
        sidx[0] = iv.x & 0xffff; sidx[1] = iv.x >> 16;
        sidx[2] = iv.y & 0xffff; sidx[3] = iv.y >> 16;
        sidx[4] = iv.z & 0xffff; sidx[5] = iv.z >> 16;
        sidx[6] = iv.w & 0xffff; sidx[7] = iv.w >> 16;
        uint4 vv[8];
#pragma unroll
        for (int q = 0; q < 8; ++q)
            vv[q] = *(const uint4*)&t3[(size_t)sidx[q] * 40 + c8];
#pragma unroll
        for (int q = 0; q < 8; ++q) {
            union { uint4 u; __half2 h[4]; } V; V.u = vv[q];
#pragma unroll
            for (int p = 0; p < 4; ++p) {
                float2 f = __half22float2(V.h[p]);
                acc[2 * p] += f.x; acc[2 * p + 1] += f.y;
            }
        }
    }
    for (; e < end; ++e) {
        int s = csr[e];
        union { uint4 u; __half2 h[4]; } V;
        V.u = *(const uint4*)&t3[(size_t)s * 40 + c8];
#pragma unroll
        for (int p = 0; p < 4; ++p) {
            float2 f = __half22float2(V.h[p]);
            acc[2 * p] += f.x; acc[2 * p + 1] += f.y;
        }
    }
    float4 r0, r1;
    r0.x = acc[0] * di + bias[c8 + 0];
    r0.y = acc[1] * di + bias[c8 + 1];
    r0.z = acc[2] * di + bias[c8 + 2];
    r0.w = acc[3] * di + bias[c8 + 3];
    r1.x = acc[4] * di + bias[c8 + 4];
    r1.y = acc[5] * di + bias[c8 + 5];
    r1.z = acc[6] * di + bias[c8 + 6];
    r1.w = acc[7] * di + bias[c8 + 7];
    *(float4*)&out[(size_t)d * 40 + c8] = r0;
    *(float4*)&out[(size_t)d * 40 + c8 + 4] = r1;
}

// ---------------- single cooperative kernel: all 5 phases, grid.sync between ----------------
struct KParams {
    const float* X; const int* src; const int* dst;
    const float* W0; const float* g0; const float* v0;
    const float* b0; const float* be0; const float* m0;
    const float* W1; const float* g1; const float* v1;
    const float* b1; const float* be1; const float* m1;
    const float* W2; const float* b2;
    int* gcur; unsigned int* part; int* rowptr; float* dinv;
    unsigned short* csr; float* Hs; __half* Hh; __half* bufh; __half* t3h;
    float* out; int n; int nE;
};

__global__ __launch_bounds__(256, 6)
void fused_all(KParams p) {
    __shared__ __align__(16) char smem[SMEM_BYTES];
    cg::grid_group grid = cg::this_grid();
    const int bid = blockIdx.x, gsz = gridDim.x;

    // phase A: edge partition (jobs 0..195) + gemm0 (jobs 196..977)
    for (int j = bid; j < PB + GB; j += gsz) {
        if (j < PB) partition_job(j, p.src, p.dst, p.gcur, p.part, p.nE, (int*)smem);
        else        gemm0_job(j - PB, p.X, p.W0, p.g0, p.v0, p.Hs, p.n, (float*)smem);
        __syncthreads();
    }
    __threadfence();
    grid.sync();

    // phase B: per-bucket CSR build + dinv + fp16 prefolded table Hh
    for (int j = bid; j < NBUCK; j += gsz)
        build_job(j, p.part, p.gcur, p.rowptr, p.dinv, p.csr, p.Hs, p.Hh, p.n, smem);
    __threadfence();
    grid.sync();

    // phase C: gather layer0 + gemm1 (BN1-scale folded) -> bufh
    for (int j = bid; j < GATHER_JOBS; j += gsz) {
        gather_job<64, true>(j, p.Hh, p.rowptr, p.csr, p.dinv, p.b0, p.g0, p.be0, p.m0, p.v0,
                             p.W1, p.g1, p.v1, p.bufh, p.n, smem);
        __syncthreads();
    }
    __threadfence();
    grid.sync();

    // phase D: gather layer1 + gemm2 (raw W2) -> t3h
    for (int j = bid; j < GATHER_JOBS; j += gsz) {
        gather_job<40, false>(j, p.bufh, p.rowptr, p.csr, p.dinv, p.b1, p.g1, p.be1, p.m1, p.v1,
                              p.W2, nullptr, nullptr, p.t3h, p.n, smem);
        __syncthreads();
    }
    __threadfence();
    grid.sync();

    // phase E: final gather + b2 -> out
    for (int j = bid; j < OUT_JOBS; j += gsz)
        gather_out_job(j, p.t3h, p.rowptr, p.csr, p.dinv, p.b2, p.out, p.n);
}

extern "C" void kernel_launch(void* const* d_in, const int* in_sizes, int n_in,
                              void* d_out, int out_size, void* d_ws, size_t ws_size,
                              hipStream_t stream) {
    KParams p;
    p.X   = (const float*)d_in[0];
    const int* ei = (const int*)d_in[1];
    p.W0  = (const float*)d_in[2];
    p.b0  = (const float*)d_in[3];
    p.g0  = (const float*)d_in[4];
    p.be0 = (const float*)d_in[5];
    p.m0  = (const float*)d_in[6];
    p.v0  = (const float*)d_in[7];
    p.W1  = (const float*)d_in[8];
    p.b1  = (const float*)d_in[9];
    p.g1  = (const float*)d_in[10];
    p.be1 = (const float*)d_in[11];
    p.m1  = (const float*)d_in[12];
    p.v1  = (const float*)d_in[13];
    p.W2  = (const float*)d_in[14];
    p.b2  = (const float*)d_in[15];
    p.out = (float*)d_out;
    p.src = ei;
    p.dst = ei + N_EDGES;
    p.n   = N_NODES;
    p.nE  = N_EDGES;

    // workspace carve-up (bytes, 16B-aligned)
    char* ws = (char*)d_ws;
    p.gcur   = (int*)(ws + 0);                       // 784 B
    p.rowptr = (int*)(ws + 1024);                    // 200004
    p.dinv   = (float*)(ws + 202240);                // 200000
    p.csr    = (unsigned short*)(ws + 402688);       // 1.6 MB
    p.Hs     = (float*)(ws + 2002944);               // 12.8 MB fp32 gemm0 out (dead after B)
    p.bufh   = (__half*)(ws + 2002944);              // 6.4 MB, aliases Hs (written phase C)
    p.t3h    = (__half*)(ws + 8402944);              // 4.0 MB (written phase D)
    p.part   = (unsigned int*)(ws + 14802944);       // 4.7 MB (dead after B)
    p.Hh     = (__half*)(ws + 21202944);             // 6.4 MB fp16 prescaled table

    hipMemsetAsync(p.gcur, 0, NBUCK * sizeof(int), stream);

    // grid = full co-resident capacity (cooperative requirement); cap at max job count
    static int g_grid = 0;
    if (g_grid == 0) {
        int maxB = 0;
        hipError_t err = hipOccupancyMaxActiveBlocksPerMultiprocessor(&maxB, fused_all, 256, 0);
        if (err != hipSuccess || maxB <= 0) maxB = 4;
        g_grid = maxB * 256;               // 256 CUs on MI355X
        if (g_grid > GATHER_JOBS) g_grid = GATHER_JOBS;
    }

    void* args[] = { (void*)&p };
    hipLaunchCooperativeKernel((void*)fused_all, dim3(g_grid), dim3(256), args, 0, stream);
}

// Round 7
// 224.609 us; speedup vs baseline: 4.2041x; 4.2041x over previous
//
#include <hip/hip_runtime.h>
#include <hip/hip_fp16.h>

#define N_NODES 50000
#define N_EDGES 800000
#define BN_EPS 1e-5f

#define NBUCK 196        // ceil(50000/256) buckets of 256 nodes
#define PART_CAP 6016    // per-bucket capacity; mean 4082, sd 64 -> 30 sigma margin
#define PB 196           // partition blocks (ceil(800000/4096))
#define GB 782           // gemm0 blocks (ceil(50000/64), 64-row tiles)

// exclusive WIDTH-thread scan in LDS; s[] is scratch (WIDTH ints). All WIDTH threads call.
template <int WIDTH>
__device__ __forceinline__ int lds_scan_excl(int* s, int t, int v) {
    s[t] = v;
    __syncthreads();
    for (int off = 1; off < WIDTH; off <<= 1) {
        int x = (t >= off) ? s[t - off] : 0;
        __syncthreads();
        s[t] += x;
        __syncthreads();
    }
    return s[t] - v;
}

// phase of a source node id (4 ranges of 12500); exact floor(s/12500) for s<50000
__device__ __forceinline__ unsigned src_phase(unsigned s) {
    return (s * 42950u) >> 29;
}

// ---------------- GEMM body: Hs[r,M] = X[r,K] @ (W .* foldscale[c]) ----------------
// 64-row tile; 256 threads = 16x16, each 4x4; K chunked by 32. (proven shape: 978-block
// grid keeps ~4 blocks/CU. 8x8/256-row variant: 76us @ 8% VALUBusy, parallelism collapse.
// r6 mega-fusion: regalloc collapse -> 40 VGPR + 250MB scratch spill, 944us. Keep split.)
template <int K, int M, bool FOLD>
__device__ __forceinline__ void gemm_body(int bid, const float* __restrict__ X,
                                          const float* __restrict__ W,
                                          const float* __restrict__ gamma,
                                          const float* __restrict__ var,
                                          float* __restrict__ Hs, int n, float* lds) {
    constexpr int KC = 32;
    float* Xs = lds;                    // 64 x 36
    float* Ws = lds + 64 * 36;          // 32 x M
    float* bns = lds + 64 * 36 + 32 * M; // M bn scales
    int tid = threadIdx.x;
    int tx = tid & 15, ty = tid >> 4;
    int row0 = bid * 64;
    if (FOLD && tid < M) bns[tid] = gamma[tid] * rsqrtf(var[tid] + BN_EPS);
    __syncthreads();
    float acc[4][4] = {};
    for (int k0 = 0; k0 < K; k0 += KC) {
#pragma unroll
        for (int it = 0; it < 2; ++it) {
            int fi = tid + it * 256;            // 512 float4s
            int r = fi >> 3, q = fi & 7;
            int row = row0 + r;
            float4 v = make_float4(0.f, 0.f, 0.f, 0.f);
            if (row < n) v = *(const float4*)&X[(size_t)row * K + k0 + q * 4];
            *(float4*)&Xs[r * 36 + q * 4] = v;
        }
#pragma unroll
        for (int it = 0; it < 2; ++it) {
            int fi = tid + it * 256;            // 512 float4s (32*M/4 with M=64)
            int kk = fi >> 4, cw = (fi & 15) * 4;
            float4 w = *(const float4*)&W[(size_t)(k0 + kk) * M + cw];
            if (FOLD) { w.x *= bns[cw]; w.y *= bns[cw + 1]; w.z *= bns[cw + 2]; w.w *= bns[cw + 3]; }
            *(float4*)&Ws[kk * M + cw] = w;
        }
        __syncthreads();
#pragma unroll 8
        for (int kk = 0; kk < KC; ++kk) {
            float4 bv = *(float4*)&Ws[kk * M + tx * 4];
#pragma unroll
            for (int j = 0; j < 4; ++j) {
                float a = Xs[(ty * 4 + j) * 36 + kk];
                acc[j][0] += a * bv.x;
                acc[j][1] += a * bv.y;
                acc[j][2] += a * bv.z;
                acc[j][3] += a * bv.w;
            }
        }
        __syncthreads();
    }
#pragma unroll
    for (int j = 0; j < 4; ++j) {
        int r = row0 + ty * 4 + j;
        if (r < n) {
            float4 v = make_float4(acc[j][0], acc[j][1], acc[j][2], acc[j][3]);
            *(float4*)&Hs[(size_t)r * M + tx * 4] = v;
        }
    }
}

// ---------------- dispatch 2: partition blocks first, then gemm0 blocks ----------------
__global__ __launch_bounds__(256, 4)
void fused_gemm0_partition_kernel(const float* __restrict__ X, const float* __restrict__ W,
                                  const float* __restrict__ gamma, const float* __restrict__ var,
                                  float* __restrict__ Hs, int n,
                                  const int* __restrict__ src, const int* __restrict__ dst,
                                  int* __restrict__ gcur, unsigned int* __restrict__ part,
                                  int nE) {
    __shared__ float lds[64 * 36 + 32 * 64 + 64];   // 17.7 KB
    if (blockIdx.x >= PB) {
        gemm_body<128, 64, true>(blockIdx.x - PB, X, W, gamma, var, Hs, n, lds);
        return;
    }
    // ---- partition branch: bin 4096 edges by dst>>8 ----
    int* lcnt  = (int*)lds;          // 196
    int* gbase = ((int*)lds) + 256;  // 196
    int t = threadIdx.x;
    int base = blockIdx.x * 4096;
    for (int i = t; i < NBUCK; i += 256) lcnt[i] = 0;
    __syncthreads();
    unsigned int val[16], pk[16];
#pragma unroll
    for (int i = 0; i < 16; ++i) {
        int e = base + i * 256 + t;
        if (e < nE) {
            unsigned s = (unsigned)src[e], d = (unsigned)dst[e];
            unsigned b = d >> 8;
            int r = atomicAdd(&lcnt[b], 1);
            val[i] = s | ((d & 255u) << 16);
            pk[i] = b | ((unsigned)r << 8);
        } else pk[i] = 0xffffffffu;
    }
    __syncthreads();
    for (int i = t; i < NBUCK; i += 256) gbase[i] = atomicAdd(&gcur[i], lcnt[i]);
    __syncthreads();
#pragma unroll
    for (int i = 0; i < 16; ++i) {
        if (pk[i] != 0xffffffffu) {
            unsigned b = pk[i] & 255u;
            unsigned p = (unsigned)gbase[b] + (pk[i] >> 8);
            if (p < PART_CAP) part[b * PART_CAP + p] = val[i];
        }
    }
}

// ---------------- dispatch 3: CSR build at 1024 threads/bucket ----------------
// r5 ran this at 256 thr/bucket on a 196-block grid (0.77 blocks/CU) -- worst parallelism
// in the pipeline. 1024 threads quarters the per-bucket serial work (histogram, scatter,
// csr copy, fp16 convert). Counting sort by (node, src-phase); NOT insertion sort (r3).
__global__ __launch_bounds__(1024, 1)
void build_kernel(const unsigned int* __restrict__ part, const int* __restrict__ gcur,
                  int* __restrict__ rowptr, float* __restrict__ dinv,
                  unsigned short* __restrict__ csr, const float* __restrict__ Hs,
                  __half* __restrict__ Hh, int n) {
    __shared__ int buf[1024];          // scan scratch (reused)
    __shared__ int nc4[1024], cur4[1024];
    __shared__ float sdinv[256];
    __shared__ unsigned short csr_lds[PART_CAP];
    __shared__ int sh[2];              // sh[0]=off, sh[1]=ec
    int b = blockIdx.x, t = threadIdx.x;

    // bucket-offset scan over gcur (1024-wide; entries >= NBUCK are 0)
    int v = (t < NBUCK) ? gcur[t] : 0;
    int ex = lds_scan_excl<1024>(buf, t, v);
    if (t == b) { sh[0] = ex; sh[1] = v; }
    nc4[t] = 0;
    __syncthreads();
    int off = sh[0];
    int ec = sh[1] < PART_CAP ? sh[1] : PART_CAP;
    const unsigned int* pb = part + (size_t)b * PART_CAP;

    // histogram per (node, phase)
    for (int i = t; i < ec; i += 1024) {
        unsigned w = pb[i];
        atomicAdd(&nc4[((w >> 16) & 255u) * 4 + src_phase(w & 0xffffu)], 1);
    }
    __syncthreads();

    // per-node prefix (nodes owned by threads 0..255)
    int c = 0, c0 = 0, c1 = 0, c2 = 0;
    if (t < 256) {
        c0 = nc4[t * 4 + 0]; c1 = nc4[t * 4 + 1]; c2 = nc4[t * 4 + 2];
        c = c0 + c1 + c2 + nc4[t * 4 + 3];
    }
    int nx = lds_scan_excl<1024>(buf, t, c);
    if (t < 256) {
        cur4[t * 4 + 0] = nx;
        cur4[t * 4 + 1] = nx + c0;
        cur4[t * 4 + 2] = nx + c0 + c1;
        cur4[t * 4 + 3] = nx + c0 + c1 + c2;
        float dv = rsqrtf((float)c + 1.0f);   // +1 = self loop
        sdinv[t] = dv;
        int node = b * 256 + t;
        if (node < n) {
            rowptr[node] = off + nx;
            dinv[node] = dv;
        }
    }
    if (b == NBUCK - 1 && t == 0) rowptr[n] = off + ec;
    __syncthreads();

    // scatter: phase-grouped within each node's sublist
    for (int i = t; i < ec; i += 1024) {
        unsigned w = pb[i];
        unsigned nd = (w >> 16) & 255u;
        unsigned s = w & 0xffffu;
        int p = atomicAdd(&cur4[nd * 4 + src_phase(s)], 1);
        csr_lds[p] = (unsigned short)s;
    }
    __syncthreads();
    for (int i = t; i < ec; i += 1024) csr[off + i] = csr_lds[i];

    // convert this bucket's Hs rows to fp16 with dinv prefold
    const float4* H4 = (const float4*)(Hs + (size_t)b * 256 * 64);
    for (int i = t; i < 4096; i += 1024) {
        int nd = i >> 4;
        int nn = b * 256 + nd;
        if (nn < n) {
            float s = sdinv[nd];
            float4 x = H4[i];
            union { uint2 u; __half2 h[2]; } U;
            U.h[0] = __floats2half2_rn(x.x * s, x.y * s);
            U.h[1] = __floats2half2_rn(x.z * s, x.w * s);
            *(uint2*)&Hh[(size_t)nn * 64 + (i & 15) * 4] = U.u;
        }
    }
}

// ---------------- fused gather (fp16 table, BN+ReLU) + next-layer GEMM ----------------
// block = 32 nodes x 8 lanes; each lane owns 8 channels (16B fp16 loads).
template <int MOUT, bool FOLD_NEXT>
__global__ __launch_bounds__(256, 6)
void gather_gemm_h(const __half* __restrict__ Hh, const int* __restrict__ rowptr,
                   const unsigned short* __restrict__ csr, const float* __restrict__ dinv,
                   const float* __restrict__ bb, const float* __restrict__ gamma,
                   const float* __restrict__ beta, const float* __restrict__ mean,
                   const float* __restrict__ var,
                   const float* __restrict__ Wn, const float* __restrict__ gn,
                   const float* __restrict__ vn, __half* __restrict__ Hout, int n) {
    __shared__ float zs[32 * 68];          // pad 68: conflict-free z reads
    __shared__ float Ws[64 * MOUT];
    int t = threadIdx.x;
    int nd = t >> 3, l = t & 7;
    int d = blockIdx.x * 32 + nd;
    int c8 = l * 8;
    for (int i = t; i < 64 * MOUT; i += 256) {
        float w = Wn[i];
        if (FOLD_NEXT) { int c = i % MOUT; w *= gn[c] * rsqrtf(vn[c] + BN_EPS); }
        Ws[i] = w;
    }
    float acc[8] = {};
    float di = 0.f;
    int beg = 0, end = 0;
    if (d < n) {
        beg = rowptr[d]; end = rowptr[d + 1];
        di = dinv[d];
        union { uint4 u; __half2 h[4]; } S;
        S.u = *(const uint4*)&Hh[(size_t)d * 64 + c8];   // self loop (prescaled)
#pragma unroll
        for (int p = 0; p < 4; ++p) {
            float2 f = __half22float2(S.h[p]);
            acc[2 * p] += f.x; acc[2 * p + 1] += f.y;
        }
    }
    int e = beg;
    int head = (beg + 7) & ~7;             // align for uint4 index loads
    if (head > end) head = end;
    for (; e < head; ++e) {
        int s = csr[e];
        union { uint4 u; __half2 h[4]; } V;
        V.u = *(const uint4*)&Hh[(size_t)s * 64 + c8];
#pragma unroll
        for (int p = 0; p < 4; ++p) {
            float2 f = __half22float2(V.h[p]);
            acc[2 * p] += f.x; acc[2 * p + 1] += f.y;
        }
    }
    for (; e + 8 <= end; e += 8) {
        uint4 iv = *(const uint4*)&csr[e];   // 8 indices in one 16B load
        int sidx[8];
        sidx[0] = iv.x & 0xffff; sidx[1] = iv.x >> 16;
        sidx[2] = iv.y & 0xffff; sidx[3] = iv.y >> 16;
        sidx[4] = iv.z & 0xffff; sidx[5] = iv.z >> 16;
        sidx[6] = iv.w & 0xffff; sidx[7] = iv.w >> 16;
        uint4 vv[8];
#pragma unroll
        for (int q = 0; q < 8; ++q)
            vv[q] = *(const uint4*)&Hh[(size_t)sidx[q] * 64 + c8];
#pragma unroll
        for (int q = 0; q < 8; ++q) {
            union { uint4 u; __half2 h[4]; } V; V.u = vv[q];
#pragma unroll
            for (int p = 0; p < 4; ++p) {
                float2 f = __half22float2(V.h[p]);
                acc[2 * p] += f.x; acc[2 * p + 1] += f.y;
            }
        }
    }
    for (; e < end; ++e) {
        int s = csr[e];
        union { uint4 u; __half2 h[4]; } V;
        V.u = *(const uint4*)&Hh[(size_t)s * 64 + c8];
#pragma unroll
        for (int p = 0; p < 4; ++p) {
            float2 f = __half22float2(V.h[p]);
            acc[2 * p] += f.x; acc[2 * p + 1] += f.y;
        }
    }
    // BN bias + ReLU of current layer, write z tile to LDS
    if (d < n) {
#pragma unroll
        for (int q = 0; q < 8; ++q) {
            int cc = c8 + q;
            float s0 = gamma[cc] * rsqrtf(var[cc] + BN_EPS);
            float bias = (bb[cc] - mean[cc]) * s0 + beta[cc];
            zs[nd * 68 + cc] = fmaxf(acc[q] * di + bias, 0.0f);
        }
    }
    __syncthreads();
    // ---- gemm phase: Hout[d, c8..c8+7] = fp16(dinv[d] * sum_k zs[nd][k] * Ws[k][c]) ----
    if (c8 < MOUT && d < n) {
        float o[8] = {};
        for (int k0 = 0; k0 < 64; k0 += 4) {
            float4 zq = *(const float4*)&zs[nd * 68 + k0];
#pragma unroll
            for (int j = 0; j < 4; ++j) {
                float zk = (&zq.x)[j];
                float4 w0 = *(const float4*)&Ws[(k0 + j) * MOUT + c8];
                float4 w1 = *(const float4*)&Ws[(k0 + j) * MOUT + c8 + 4];
                o[0] += zk * w0.x; o[1] += zk * w0.y; o[2] += zk * w0.z; o[3] += zk * w0.w;
                o[4] += zk * w1.x; o[5] += zk * w1.y; o[6] += zk * w1.z; o[7] += zk * w1.w;
            }
        }
        union { uint4 u; __half2 h[4]; } O;
#pragma unroll
        for (int p = 0; p < 4; ++p)
            O.h[p] = __floats2half2_rn(o[2 * p] * di, o[2 * p + 1] * di);
        *(uint4*)&Hout[(size_t)d * MOUT + c8] = O.u;
    }
}

// ---------------- final gather over fp16 40-ch rows; fp32 out ----------------
// block = 50 nodes x 5 lanes (250 active threads); lane owns 8 channels (16B loads).
__global__ __launch_bounds__(256, 8)
void gather_out_kernel(const __half* __restrict__ t3, const int* __restrict__ rowptr,
                       const unsigned short* __restrict__ csr, const float* __restrict__ dinv,
                       const float* __restrict__ bias, float* __restrict__ out, int n) {
    int t = threadIdx.x;
    if (t >= 250) return;
    int nd = t / 5, l = t % 5;
    int d = blockIdx.x * 50 + nd;
    if (d >= n) return;
    int c8 = l * 8;
    int beg = rowptr[d], end = rowptr[d + 1];
    float di = dinv[d];
    float acc[8];
    {
        union { uint4 u; __half2 h[4]; } S;
        S.u = *(const uint4*)&t3[(size_t)d * 40 + c8];
#pragma unroll
        for (int p = 0; p < 4; ++p) {
            float2 f = __half22float2(S.h[p]);
            acc[2 * p] = f.x; acc[2 * p + 1] = f.y;
        }
    }
    int e = beg;
    int head = (beg + 7) & ~7;
    if (head > end) head = end;
    for (; e < head; ++e) {
        int s = csr[e];
        union { uint4 u; __half2 h[4]; } V;
        V.u = *(const uint4*)&t3[(size_t)s * 40 + c8];
#pragma unroll
        for (int p = 0; p < 4; ++p) {
            float2 f = __half22float2(V.h[p]);
            acc[2 * p] += f.x; acc[2 * p + 1] += f.y;
        }
    }
    for (; e + 8 <= end; e += 8) {
        uint4 iv = *(const uint4*)&csr[e];
        int sidx[8];
        sidx[0] = iv.x & 0xffff; sidx[1] = iv.x >> 16;
        sidx[2] = iv.y & 0xffff; sidx[3] = iv.y >> 16;
        sidx[4] = iv.z & 0xffff; sidx[5] = iv.z >> 16;
        sidx[6] = iv.w & 0xffff; sidx[7] = iv.w >> 16;
        uint4 vv[8];
#pragma unroll
        for (int q = 0; q < 8; ++q)
            vv[q] = *(const uint4*)&t3[(size_t)sidx[q] * 40 + c8];
#pragma unroll
        for (int q = 0; q < 8; ++q) {
            union { uint4 u; __half2 h[4]; } V; V.u = vv[q];
#pragma unroll
            for (int p = 0; p < 4; ++p) {
                float2 f = __half22float2(V.h[p]);
                acc[2 * p] += f.x; acc[2 * p + 1] += f.y;
            }
        }
    }
    for (; e < end; ++e) {
        int s = csr[e];
        union { uint4 u; __half2 h[4]; } V;
        V.u = *(const uint4*)&t3[(size_t)s * 40 + c8];
#pragma unroll
        for (int p = 0; p < 4; ++p) {
            float2 f = __half22float2(V.h[p]);
            acc[2 * p] += f.x; acc[2 * p + 1] += f.y;
        }
    }
    float4 r0, r1;
    r0.x = acc[0] * di + bias[c8 + 0];
    r0.y = acc[1] * di + bias[c8 + 1];
    r0.z = acc[2] * di + bias[c8 + 2];
    r0.w = acc[3] * di + bias[c8 + 3];
    r1.x = acc[4] * di + bias[c8 + 4];
    r1.y = acc[5] * di + bias[c8 + 5];
    r1.z = acc[6] * di + bias[c8 + 6];
    r1.w = acc[7] * di + bias[c8 + 7];
    *(float4*)&out[(size_t)d * 40 + c8] = r0;
    *(float4*)&out[(size_t)d * 40 + c8 + 4] = r1;
}

extern "C" void kernel_launch(void* const* d_in, const int* in_sizes, int n_in,
                              void* d_out, int out_size, void* d_ws, size_t ws_size,
                              hipStream_t stream) {
    const float* x      = (const float*)d_in[0];
    const int*   ei     = (const int*)d_in[1];
    const float* W0     = (const float*)d_in[2];
    const float* b0     = (const float*)d_in[3];
    const float* gamma0 = (const float*)d_in[4];
    const float* beta0  = (const float*)d_in[5];
    const float* mean0  = (const float*)d_in[6];
    const float* var0   = (const float*)d_in[7];
    const float* W1     = (const float*)d_in[8];
    const float* b1     = (const float*)d_in[9];
    const float* gamma1 = (const float*)d_in[10];
    const float* beta1  = (const float*)d_in[11];
    const float* mean1  = (const float*)d_in[12];
    const float* var1   = (const float*)d_in[13];
    const float* W2     = (const float*)d_in[14];
    const float* b2     = (const float*)d_in[15];
    float* out = (float*)d_out;

    const int* srcp = ei;
    const int* dstp = ei + N_EDGES;
    const int N = N_NODES, E = N_EDGES;

    // workspace carve-up (bytes, 16B-aligned). Total footprint 27.6 MB.
    char* ws = (char*)d_ws;
    int*            gcur   = (int*)(ws + 0);          // 784 B
    int*            rowptr = (int*)(ws + 1024);       // 200004
    float*          dinv   = (float*)(ws + 202240);   // 200000
    unsigned short* csr    = (unsigned short*)(ws + 402688);   // 1.6 MB
    float*          Hs     = (float*)(ws + 2002944);  // 12.8 MB fp32 gemm0 out (dead after d3)
    __half*         bufh   = (__half*)(ws + 2002944); // 6.4 MB, aliases Hs (written in d4)
    __half*         t3h    = (__half*)(ws + 8402944); // 4.0 MB (written in d5)
    unsigned int*   part   = (unsigned int*)(ws + 14802944);   // 4.7 MB (dead after d3)
    __half*         Hh     = (__half*)(ws + 21202944);         // 6.4 MB fp16 prescaled table

    hipMemsetAsync(gcur, 0, NBUCK * sizeof(int), stream);

    // d2: partition (blocks 0..195) + gemm0 (BN0-folded, 64-row tiles) in one dispatch
    fused_gemm0_partition_kernel<<<PB + GB, 256, 0, stream>>>(
        x, W0, gamma0, var0, Hs, N, srcp, dstp, gcur, part, E);

    // d3: CSR build (1024 thr/bucket) + rowptr + dinv + fp16 prefolded table Hh
    build_kernel<<<NBUCK, 1024, 0, stream>>>(part, gcur, rowptr, dinv, csr, Hs, Hh, N);

    // d4: gather layer0 (fp16 rows, BN0 bias+relu) + gemm1 (BN1-scale folded) -> bufh (fp16)
    gather_gemm_h<64, true><<<(N + 31) / 32, 256, 0, stream>>>(
        Hh, rowptr, csr, dinv, b0, gamma0, beta0, mean0, var0,
        W1, gamma1, var1, bufh, N);

    // d5: gather layer1 (fp16 rows, BN1 bias+relu) + gemm2 (raw W2) -> t3h (fp16, 40ch)
    gather_gemm_h<40, false><<<(N + 31) / 32, 256, 0, stream>>>(
        bufh, rowptr, csr, dinv, b1, gamma1, beta1, mean1, var1,
        W2, nullptr, nullptr, t3h, N);

    // d6: final gather over t3h + b2 -> fp32 out
    gather_out_kernel<<<N / 50, 256, 0, stream>>>(t3h, rowptr, csr, dinv, b2, out, N);
}

// Round 9
// 224.098 us; speedup vs baseline: 4.2137x; 1.0023x over previous
//
#include <hip/hip_runtime.h>
#include <hip/hip_fp16.h>

#define N_NODES 50000
#define N_EDGES 800000
#define BN_EPS 1e-5f

#define NBUCK 196        // ceil(50000/256) buckets of 256 nodes
#define PART_CAP 6016    // per-bucket capacity; mean 4082, sd 64 -> 30 sigma margin
#define PB 196           // partition blocks (ceil(800000/4096))
#define GB 782           // gemm0 blocks (ceil(50000/64), 64-row tiles)

// exclusive WIDTH-thread scan in LDS; s[] is scratch (WIDTH ints). All WIDTH threads call.
template <int WIDTH>
__device__ __forceinline__ int lds_scan_excl(int* s, int t, int v) {
    s[t] = v;
    __syncthreads();
    for (int off = 1; off < WIDTH; off <<= 1) {
        int x = (t >= off) ? s[t - off] : 0;
        __syncthreads();
        s[t] += x;
        __syncthreads();
    }
    return s[t] - v;
}

// phase of a source node id (4 ranges of 12500); exact floor(s/12500) for s<50000
__device__ __forceinline__ unsigned src_phase(unsigned s) {
    return (s * 42950u) >> 29;
}

// ---------------- GEMM body: Hs[r,M] = X[r,K] @ (W .* foldscale[c]) ----------------
// 64-row tile; 256 threads = 16x16, each 4x4; K chunked by 32. (proven shape: 978-block
// grid keeps ~4 blocks/CU. 8x8/256-row variant: 76us @ 8% VALUBusy, parallelism collapse.
// r6 mega-fusion: regalloc collapse -> 40 VGPR + 250MB scratch spill, 944us. Keep split.)
template <int K, int M, bool FOLD>
__device__ __forceinline__ void gemm_body(int bid, const float* __restrict__ X,
                                          const float* __restrict__ W,
                                          const float* __restrict__ gamma,
                                          const float* __restrict__ var,
                                          float* __restrict__ Hs, int n, float* lds) {
    constexpr int KC = 32;
    float* Xs = lds;                    // 64 x 36
    float* Ws = lds + 64 * 36;          // 32 x M
    float* bns = lds + 64 * 36 + 32 * M; // M bn scales
    int tid = threadIdx.x;
    int tx = tid & 15, ty = tid >> 4;
    int row0 = bid * 64;
    if (FOLD && tid < M) bns[tid] = gamma[tid] * rsqrtf(var[tid] + BN_EPS);
    __syncthreads();
    float acc[4][4] = {};
    for (int k0 = 0; k0 < K; k0 += KC) {
#pragma unroll
        for (int it = 0; it < 2; ++it) {
            int fi = tid + it * 256;            // 512 float4s
            int r = fi >> 3, q = fi & 7;
            int row = row0 + r;
            float4 v = make_float4(0.f, 0.f, 0.f, 0.f);
            if (row < n) v = *(const float4*)&X[(size_t)row * K + k0 + q * 4];
            *(float4*)&Xs[r * 36 + q * 4] = v;
        }
#pragma unroll
        for (int it = 0; it < 2; ++it) {
            int fi = tid + it * 256;            // 512 float4s (32*M/4 with M=64)
            int kk = fi >> 4, cw = (fi & 15) * 4;
            float4 w = *(const float4*)&W[(size_t)(k0 + kk) * M + cw];
            if (FOLD) { w.x *= bns[cw]; w.y *= bns[cw + 1]; w.z *= bns[cw + 2]; w.w *= bns[cw + 3]; }
            *(float4*)&Ws[kk * M + cw] = w;
        }
        __syncthreads();
#pragma unroll 8
        for (int kk = 0; kk < KC; ++kk) {
            float4 bv = *(float4*)&Ws[kk * M + tx * 4];
#pragma unroll
            for (int j = 0; j < 4; ++j) {
                float a = Xs[(ty * 4 + j) * 36 + kk];
                acc[j][0] += a * bv.x;
                acc[j][1] += a * bv.y;
                acc[j][2] += a * bv.z;
                acc[j][3] += a * bv.w;
            }
        }
        __syncthreads();
    }
#pragma unroll
    for (int j = 0; j < 4; ++j) {
        int r = row0 + ty * 4 + j;
        if (r < n) {
            float4 v = make_float4(acc[j][0], acc[j][1], acc[j][2], acc[j][3]);
            *(float4*)&Hs[(size_t)r * M + tx * 4] = v;
        }
    }
}

// ---------------- dispatch 2: partition blocks first, then gemm0 blocks ----------------
__global__ __launch_bounds__(256, 4)
void fused_gemm0_partition_kernel(const float* __restrict__ X, const float* __restrict__ W,
                                  const float* __restrict__ gamma, const float* __restrict__ var,
                                  float* __restrict__ Hs, int n,
                                  const int* __restrict__ src, const int* __restrict__ dst,
                                  int* __restrict__ gcur, unsigned int* __restrict__ part,
                                  int nE) {
    __shared__ float lds[64 * 36 + 32 * 64 + 64];   // 17.7 KB
    if (blockIdx.x >= PB) {
        gemm_body<128, 64, true>(blockIdx.x - PB, X, W, gamma, var, Hs, n, lds);
        return;
    }
    // ---- partition branch: bin 4096 edges by dst>>8 ----
    int* lcnt  = (int*)lds;          // 196
    int* gbase = ((int*)lds) + 256;  // 196
    int t = threadIdx.x;
    int base = blockIdx.x * 4096;
    for (int i = t; i < NBUCK; i += 256) lcnt[i] = 0;
    __syncthreads();
    unsigned int val[16], pk[16];
#pragma unroll
    for (int i = 0; i < 16; ++i) {
        int e = base + i * 256 + t;
        if (e < nE) {
            unsigned s = (unsigned)src[e], d = (unsigned)dst[e];
            unsigned b = d >> 8;
            int r = atomicAdd(&lcnt[b], 1);
            val[i] = s | ((d & 255u) << 16);
            pk[i] = b | ((unsigned)r << 8);
        } else pk[i] = 0xffffffffu;
    }
    __syncthreads();
    for (int i = t; i < NBUCK; i += 256) gbase[i] = atomicAdd(&gcur[i], lcnt[i]);
    __syncthreads();
#pragma unroll
    for (int i = 0; i < 16; ++i) {
        if (pk[i] != 0xffffffffu) {
            unsigned b = pk[i] & 255u;
            unsigned p = (unsigned)gbase[b] + (pk[i] >> 8);
            if (p < PART_CAP) part[b * PART_CAP + p] = val[i];
        }
    }
}

// ---------------- dispatch 3: CSR build at 1024 threads/bucket ----------------
// (1024-wide proven r7: -6.5us vs 256-wide. Counting sort by (node, src-phase).)
__global__ __launch_bounds__(1024, 1)
void build_kernel(const unsigned int* __restrict__ part, const int* __restrict__ gcur,
                  int* __restrict__ rowptr, float* __restrict__ dinv,
                  unsigned short* __restrict__ csr, const float* __restrict__ Hs,
                  __half* __restrict__ Hh, int n) {
    __shared__ int buf[1024];          // scan scratch (reused)
    __shared__ int nc4[1024], cur4[1024];
    __shared__ float sdinv[256];
    __shared__ unsigned short csr_lds[PART_CAP];
    __shared__ int sh[2];              // sh[0]=off, sh[1]=ec
    int b = blockIdx.x, t = threadIdx.x;

    // bucket-offset scan over gcur (1024-wide; entries >= NBUCK are 0)
    int v = (t < NBUCK) ? gcur[t] : 0;
    int ex = lds_scan_excl<1024>(buf, t, v);
    if (t == b) { sh[0] = ex; sh[1] = v; }
    nc4[t] = 0;
    __syncthreads();
    int off = sh[0];
    int ec = sh[1] < PART_CAP ? sh[1] : PART_CAP;
    const unsigned int* pb = part + (size_t)b * PART_CAP;

    // histogram per (node, phase)
    for (int i = t; i < ec; i += 1024) {
        unsigned w = pb[i];
        atomicAdd(&nc4[((w >> 16) & 255u) * 4 + src_phase(w & 0xffffu)], 1);
    }
    __syncthreads();

    // per-node prefix (nodes owned by threads 0..255)
    int c = 0, c0 = 0, c1 = 0, c2 = 0;
    if (t < 256) {
        c0 = nc4[t * 4 + 0]; c1 = nc4[t * 4 + 1]; c2 = nc4[t * 4 + 2];
        c = c0 + c1 + c2 + nc4[t * 4 + 3];
    }
    int nx = lds_scan_excl<1024>(buf, t, c);
    if (t < 256) {
        cur4[t * 4 + 0] = nx;
        cur4[t * 4 + 1] = nx + c0;
        cur4[t * 4 + 2] = nx + c0 + c1;
        cur4[t * 4 + 3] = nx + c0 + c1 + c2;
        float dv = rsqrtf((float)c + 1.0f);   // +1 = self loop
        sdinv[t] = dv;
        int node = b * 256 + t;
        if (node < n) {
            rowptr[node] = off + nx;
            dinv[node] = dv;
        }
    }
    if (b == NBUCK - 1 && t == 0) rowptr[n] = off + ec;
    __syncthreads();

    // scatter: phase-grouped within each node's sublist
    for (int i = t; i < ec; i += 1024) {
        unsigned w = pb[i];
        unsigned nd = (w >> 16) & 255u;
        unsigned s = w & 0xffffu;
        int p = atomicAdd(&cur4[nd * 4 + src_phase(s)], 1);
        csr_lds[p] = (unsigned short)s;
    }
    __syncthreads();
    for (int i = t; i < ec; i += 1024) csr[off + i] = csr_lds[i];

    // convert this bucket's Hs rows to fp16 with dinv prefold
    const float4* H4 = (const float4*)(Hs + (size_t)b * 256 * 64);
    for (int i = t; i < 4096; i += 1024) {
        int nd = i >> 4;
        int nn = b * 256 + nd;
        if (nn < n) {
            float s = sdinv[nd];
            float4 x = H4[i];
            union { uint2 u; __half2 h[2]; } U;
            U.h[0] = __floats2half2_rn(x.x * s, x.y * s);
            U.h[1] = __floats2half2_rn(x.z * s, x.w * s);
            *(uint2*)&Hh[(size_t)nn * 64 + (i & 15) * 4] = U.u;
        }
    }
}

// ---------------- fused gather (fp16 table, BN+ReLU) + next-layer GEMM ----------------
// block = 32 nodes x 8 lanes; each lane owns 8 channels (16B fp16 loads).
// WAVE-DECOUPLED: gemm reads zs rows of its OWN wave's 8 nodes only, so the z handoff
// needs no block barrier -- wave64 lockstep + s_waitcnt lgkmcnt(0) + sched_barrier(0)
// suffices (guide rule #18). The only __syncthreads is right after Ws staging. Waves flow
// gather->gemm independently; tail coupling drops from max-of-32 to max-of-8 node degrees.
template <int MOUT, bool FOLD_NEXT>
__global__ __launch_bounds__(256, 6)
void gather_gemm_h(const __half* __restrict__ Hh, const int* __restrict__ rowptr,
                   const unsigned short* __restrict__ csr, const float* __restrict__ dinv,
                   const float* __restrict__ bb, const float* __restrict__ gamma,
                   const float* __restrict__ beta, const float* __restrict__ mean,
                   const float* __restrict__ var,
                   const float* __restrict__ Wn, const float* __restrict__ gn,
                   const float* __restrict__ vn, __half* __restrict__ Hout, int n) {
    __shared__ float zs[32 * 68];          // pad 68: conflict-free b128 broadcast per node
    __shared__ float Ws[64 * MOUT];
    int t = threadIdx.x;
    int nd = t >> 3, l = t & 7;
    int d = blockIdx.x * 32 + nd;
    int c8 = l * 8;
    // stage next-layer W (BN-fold if requested); barrier BEFORE the long gather phase
    for (int i = t; i < 64 * MOUT; i += 256) {
        float w = Wn[i];
        if (FOLD_NEXT) { int c = i % MOUT; w *= gn[c] * rsqrtf(vn[c] + BN_EPS); }
        Ws[i] = w;
    }
    __syncthreads();
    float acc[8] = {};
    float di = 0.f;
    int beg = 0, end = 0;
    if (d < n) {
        beg = rowptr[d]; end = rowptr[d + 1];
        di = dinv[d];
        union { uint4 u; __half2 h[4]; } S;
        S.u = *(const uint4*)&Hh[(size_t)d * 64 + c8];   // self loop (prescaled)
#pragma unroll
        for (int p = 0; p < 4; ++p) {
            float2 f = __half22float2(S.h[p]);
            acc[2 * p] += f.x; acc[2 * p + 1] += f.y;
        }
    }
    int e = beg;
    int head = (beg + 7) & ~7;             // align for uint4 index loads
    if (head > end) head = end;
    for (; e < head; ++e) {
        int s = csr[e];
        union { uint4 u; __half2 h[4]; } V;
        V.u = *(const uint4*)&Hh[(size_t)s * 64 + c8];
#pragma unroll
        for (int p = 0; p < 4; ++p) {
            float2 f = __half22float2(V.h[p]);
            acc[2 * p] += f.x; acc[2 * p + 1] += f.y;
        }
    }
    for (; e + 8 <= end; e += 8) {
        uint4 iv = *(const uint4*)&csr[e];   // 8 indices in one 16B load
        int sidx[8];
        sidx[0] = iv.x & 0xffff; sidx[1] = iv.x >> 16;
        sidx[2] = iv.y & 0xffff; sidx[3] = iv.y >> 16;
        sidx[4] = iv.z & 0xffff; sidx[5] = iv.z >> 16;
        sidx[6] = iv.w & 0xffff; sidx[7] = iv.w >> 16;
        uint4 vv[8];
#pragma unroll
        for (int q = 0; q < 8; ++q)
            vv[q] = *(const uint4*)&Hh[(size_t)sidx[q] * 64 + c8];
#pragma unroll
        for (int q = 0; q < 8; ++q) {
            union { uint4 u; __half2 h[4]; } V; V.u = vv[q];
#pragma unroll
            for (int p = 0; p < 4; ++p) {
                float2 f = __half22float2(V.h[p]);
                acc[2 * p] += f.x; acc[2 * p + 1] += f.y;
            }
        }
    }
    for (; e < end; ++e) {
        int s = csr[e];
        union { uint4 u; __half2 h[4]; } V;
        V.u = *(const uint4*)&Hh[(size_t)s * 64 + c8];
#pragma unroll
        for (int p = 0; p < 4; ++p) {
            float2 f = __half22float2(V.h[p]);
            acc[2 * p] += f.x; acc[2 * p + 1] += f.y;
        }
    }
    // BN bias + ReLU of current layer, write z tile to LDS (own wave's rows only)
    if (d < n) {
#pragma unroll
        for (int q = 0; q < 8; ++q) {
            int cc = c8 + q;
            float s0 = gamma[cc] * rsqrtf(var[cc] + BN_EPS);
            float bias = (bb[cc] - mean[cc]) * s0 + beta[cc];
            zs[nd * 68 + cc] = fmaxf(acc[q] * di + bias, 0.0f);
        }
    }
    // wave-local handoff: drain this wave's ds_writes; lockstep makes all 8 lanes' z visible.
    // sched_barrier(0) pins ordering against compiler hoisting (guide rule #18).
    asm volatile("s_waitcnt lgkmcnt(0)" ::: "memory");
    __builtin_amdgcn_sched_barrier(0);
    // ---- gemm phase: Hout[d, c8..c8+7] = fp16(dinv[d] * sum_k zs[nd][k] * Ws[k][c]) ----
    if (c8 < MOUT && d < n) {
        float o[8] = {};
        for (int k0 = 0; k0 < 64; k0 += 4) {
            float4 zq = *(const float4*)&zs[nd * 68 + k0];
#pragma unroll
            for (int j = 0; j < 4; ++j) {
                float zk = (&zq.x)[j];
                float4 w0 = *(const float4*)&Ws[(k0 + j) * MOUT + c8];
                float4 w1 = *(const float4*)&Ws[(k0 + j) * MOUT + c8 + 4];
                o[0] += zk * w0.x; o[1] += zk * w0.y; o[2] += zk * w0.z; o[3] += zk * w0.w;
                o[4] += zk * w1.x; o[5] += zk * w1.y; o[6] += zk * w1.z; o[7] += zk * w1.w;
            }
        }
        union { uint4 u; __half2 h[4]; } O;
#pragma unroll
        for (int p = 0; p < 4; ++p)
            O.h[p] = __floats2half2_rn(o[2 * p] * di, o[2 * p + 1] * di);
        *(uint4*)&Hout[(size_t)d * MOUT + c8] = O.u;
    }
}

// ---------------- final gather over fp16 40-ch rows; fp32 out ----------------
// block = 50 nodes x 5 lanes (250 active threads); lane owns 8 channels (16B loads).
__global__ __launch_bounds__(256, 8)
void gather_out_kernel(const __half* __restrict__ t3, const int* __restrict__ rowptr,
                       const unsigned short* __restrict__ csr, const float* __restrict__ dinv,
                       const float* __restrict__ bias, float* __restrict__ out, int n) {
    int t = threadIdx.x;
    if (t >= 250) return;
    int nd = t / 5, l = t % 5;
    int d = blockIdx.x * 50 + nd;
    if (d >= n) return;
    int c8 = l * 8;
    int beg = rowptr[d], end = rowptr[d + 1];
    float di = dinv[d];
    float acc[8];
    {
        union { uint4 u; __half2 h[4]; } S;
        S.u = *(const uint4*)&t3[(size_t)d * 40 + c8];
#pragma unroll
        for (int p = 0; p < 4; ++p) {
            float2 f = __half22float2(S.h[p]);
            acc[2 * p] = f.x; acc[2 * p + 1] = f.y;
        }
    }
    int e = beg;
    int head = (beg + 7) & ~7;
    if (head > end) head = end;
    for (; e < head; ++e) {
        int s = csr[e];
        union { uint4 u; __half2 h[4]; } V;
        V.u = *(const uint4*)&t3[(size_t)s * 40 + c8];
#pragma unroll
        for (int p = 0; p < 4; ++p) {
            float2 f = __half22float2(V.h[p]);
            acc[2 * p] += f.x; acc[2 * p + 1] += f.y;
        }
    }
    for (; e + 8 <= end; e += 8) {
        uint4 iv = *(const uint4*)&csr[e];
        int sidx[8];
        sidx[0] = iv.x & 0xffff; sidx[1] = iv.x >> 16;
        sidx[2] = iv.y & 0xffff; sidx[3] = iv.y >> 16;
        sidx[4] = iv.z & 0xffff; sidx[5] = iv.z >> 16;
        sidx[6] = iv.w & 0xffff; sidx[7] = iv.w >> 16;
        uint4 vv[8];
#pragma unroll
        for (int q = 0; q < 8; ++q)
            vv[q] = *(const uint4*)&t3[(size_t)sidx[q] * 40 + c8];
#pragma unroll
        for (int q = 0; q < 8; ++q) {
            union { uint4 u; __half2 h[4]; } V; V.u = vv[q];
#pragma unroll
            for (int p = 0; p < 4; ++p) {
                float2 f = __half22float2(V.h[p]);
                acc[2 * p] += f.x; acc[2 * p + 1] += f.y;
            }
        }
    }
    for (; e < end; ++e) {
        int s = csr[e];
        union { uint4 u; __half2 h[4]; } V;
        V.u = *(const uint4*)&t3[(size_t)s * 40 + c8];
#pragma unroll
        for (int p = 0; p < 4; ++p) {
            float2 f = __half22float2(V.h[p]);
            acc[2 * p] += f.x; acc[2 * p + 1] += f.y;
        }
    }
    float4 r0, r1;
    r0.x = acc[0] * di + bias[c8 + 0];
    r0.y = acc[1] * di + bias[c8 + 1];
    r0.z = acc[2] * di + bias[c8 + 2];
    r0.w = acc[3] * di + bias[c8 + 3];
    r1.x = acc[4] * di + bias[c8 + 4];
    r1.y = acc[5] * di + bias[c8 + 5];
    r1.z = acc[6] * di + bias[c8 + 6];
    r1.w = acc[7] * di + bias[c8 + 7];
    *(float4*)&out[(size_t)d * 40 + c8] = r0;
    *(float4*)&out[(size_t)d * 40 + c8 + 4] = r1;
}

extern "C" void kernel_launch(void* const* d_in, const int* in_sizes, int n_in,
                              void* d_out, int out_size, void* d_ws, size_t ws_size,
                              hipStream_t stream) {
    const float* x      = (const float*)d_in[0];
    const int*   ei     = (const int*)d_in[1];
    const float* W0     = (const float*)d_in[2];
    const float* b0     = (const float*)d_in[3];
    const float* gamma0 = (const float*)d_in[4];
    const float* beta0  = (const float*)d_in[5];
    const float* mean0  = (const float*)d_in[6];
    const float* var0   = (const float*)d_in[7];
    const float* W1     = (const float*)d_in[8];
    const float* b1     = (const float*)d_in[9];
    const float* gamma1 = (const float*)d_in[10];
    const float* beta1  = (const float*)d_in[11];
    const float* mean1  = (const float*)d_in[12];
    const float* var1   = (const float*)d_in[13];
    const float* W2     = (const float*)d_in[14];
    const float* b2     = (const float*)d_in[15];
    float* out = (float*)d_out;

    const int* srcp = ei;
    const int* dstp = ei + N_EDGES;
    const int N = N_NODES, E = N_EDGES;

    // workspace carve-up (bytes, 16B-aligned). Total footprint 27.6 MB.
    char* ws = (char*)d_ws;
    int*            gcur   = (int*)(ws + 0);          // 784 B
    int*            rowptr = (int*)(ws + 1024);       // 200004
    float*          dinv   = (float*)(ws + 202240);   // 200000
    unsigned short* csr    = (unsigned short*)(ws + 402688);   // 1.6 MB
    float*          Hs     = (float*)(ws + 2002944);  // 12.8 MB fp32 gemm0 out (dead after d3)
    __half*         bufh   = (__half*)(ws + 2002944); // 6.4 MB, aliases Hs (written in d4)
    __half*         t3h    = (__half*)(ws + 8402944); // 4.0 MB (written in d5)
    unsigned int*   part   = (unsigned int*)(ws + 14802944);   // 4.7 MB (dead after d3)
    __half*         Hh     = (__half*)(ws + 21202944);         // 6.4 MB fp16 prescaled table

    hipMemsetAsync(gcur, 0, NBUCK * sizeof(int), stream);

    // d2: partition (blocks 0..195) + gemm0 (BN0-folded, 64-row tiles) in one dispatch
    fused_gemm0_partition_kernel<<<PB + GB, 256, 0, stream>>>(
        x, W0, gamma0, var0, Hs, N, srcp, dstp, gcur, part, E);

    // d3: CSR build (1024 thr/bucket) + rowptr + dinv + fp16 prefolded table Hh
    build_kernel<<<NBUCK, 1024, 0, stream>>>(part, gcur, rowptr, dinv, csr, Hs, Hh, N);

    // d4: gather layer0 (fp16 rows, BN0 bias+relu) + gemm1 (BN1-scale folded) -> bufh (fp16)
    gather_gemm_h<64, true><<<(N + 31) / 32, 256, 0, stream>>>(
        Hh, rowptr, csr, dinv, b0, gamma0, beta0, mean0, var0,
        W1, gamma1, var1, bufh, N);

    // d5: gather layer1 (fp16 rows, BN1 bias+relu) + gemm2 (raw W2) -> t3h (fp16, 40ch)
    gather_gemm_h<40, false><<<(N + 31) / 32, 256, 0, stream>>>(
        bufh, rowptr, csr, dinv, b1, gamma1, beta1, mean1, var1,
        W2, nullptr, nullptr, t3h, N);

    // d6: final gather over t3h + b2 -> fp32 out
    gather_out_kernel<<<N / 50, 256, 0, stream>>>(t3h, rowptr, csr, dinv, b2, out, N);
}

// Round 10
// 209.602 us; speedup vs baseline: 4.5051x; 1.0692x over previous
//
#include <hip/hip_runtime.h>
#include <hip/hip_fp16.h>

#define N_NODES 50000
#define N_EDGES 800000
#define BN_EPS 1e-5f

#define NBUCK 196        // ceil(50000/256) buckets of 256 nodes
#define PART_CAP 6016    // per-bucket capacity; mean 4082, sd 64 -> 30 sigma margin
#define PB 196           // partition blocks (ceil(800000/4096))
#define GB 782           // gemm0 blocks (ceil(50000/64), 64-row tiles)

// exclusive WIDTH-thread scan in LDS; s[] is scratch (WIDTH ints). All WIDTH threads call.
template <int WIDTH>
__device__ __forceinline__ int lds_scan_excl(int* s, int t, int v) {
    s[t] = v;
    __syncthreads();
    for (int off = 1; off < WIDTH; off <<= 1) {
        int x = (t >= off) ? s[t - off] : 0;
        __syncthreads();
        s[t] += x;
        __syncthreads();
    }
    return s[t] - v;
}

// phase of a source node id (4 ranges of 12500); exact floor(s/12500) for s<50000
__device__ __forceinline__ unsigned src_phase(unsigned s) {
    return (s * 42950u) >> 29;
}

// ---------------- GEMM body: Hs[r,M] = X[r,K] @ (W .* foldscale[c]) ----------------
// 64-row tile; 256 threads = 16x16, each 4x4; K chunked by 32. (proven shape: 978-block
// grid keeps ~4 blocks/CU. 8x8/256-row variant: 76us @ 8% VALUBusy, parallelism collapse.
// r6 mega-fusion: regalloc collapse -> 40 VGPR + 250MB scratch spill, 944us. Keep split.)
template <int K, int M, bool FOLD>
__device__ __forceinline__ void gemm_body(int bid, const float* __restrict__ X,
                                          const float* __restrict__ W,
                                          const float* __restrict__ gamma,
                                          const float* __restrict__ var,
                                          float* __restrict__ Hs, int n, float* lds) {
    constexpr int KC = 32;
    float* Xs = lds;                    // 64 x 36
    float* Ws = lds + 64 * 36;          // 32 x M
    float* bns = lds + 64 * 36 + 32 * M; // M bn scales
    int tid = threadIdx.x;
    int tx = tid & 15, ty = tid >> 4;
    int row0 = bid * 64;
    if (FOLD && tid < M) bns[tid] = gamma[tid] * rsqrtf(var[tid] + BN_EPS);
    __syncthreads();
    float acc[4][4] = {};
    for (int k0 = 0; k0 < K; k0 += KC) {
#pragma unroll
        for (int it = 0; it < 2; ++it) {
            int fi = tid + it * 256;            // 512 float4s
            int r = fi >> 3, q = fi & 7;
            int row = row0 + r;
            float4 v = make_float4(0.f, 0.f, 0.f, 0.f);
            if (row < n) v = *(const float4*)&X[(size_t)row * K + k0 + q * 4];
            *(float4*)&Xs[r * 36 + q * 4] = v;
        }
#pragma unroll
        for (int it = 0; it < 2; ++it) {
            int fi = tid + it * 256;            // 512 float4s (32*M/4 with M=64)
            int kk = fi >> 4, cw = (fi & 15) * 4;
            float4 w = *(const float4*)&W[(size_t)(k0 + kk) * M + cw];
            if (FOLD) { w.x *= bns[cw]; w.y *= bns[cw + 1]; w.z *= bns[cw + 2]; w.w *= bns[cw + 3]; }
            *(float4*)&Ws[kk * M + cw] = w;
        }
        __syncthreads();
#pragma unroll 8
        for (int kk = 0; kk < KC; ++kk) {
            float4 bv = *(float4*)&Ws[kk * M + tx * 4];
#pragma unroll
            for (int j = 0; j < 4; ++j) {
                float a = Xs[(ty * 4 + j) * 36 + kk];
                acc[j][0] += a * bv.x;
                acc[j][1] += a * bv.y;
                acc[j][2] += a * bv.z;
                acc[j][3] += a * bv.w;
            }
        }
        __syncthreads();
    }
#pragma unroll
    for (int j = 0; j < 4; ++j) {
        int r = row0 + ty * 4 + j;
        if (r < n) {
            float4 v = make_float4(acc[j][0], acc[j][1], acc[j][2], acc[j][3]);
            *(float4*)&Hs[(size_t)r * M + tx * 4] = v;
        }
    }
}

// ---------------- dispatch 2: partition blocks first, then gemm0 blocks ----------------
__global__ __launch_bounds__(256, 4)
void fused_gemm0_partition_kernel(const float* __restrict__ X, const float* __restrict__ W,
                                  const float* __restrict__ gamma, const float* __restrict__ var,
                                  float* __restrict__ Hs, int n,
                                  const int* __restrict__ src, const int* __restrict__ dst,
                                  int* __restrict__ gcur, unsigned int* __restrict__ part,
                                  int nE) {
    __shared__ float lds[64 * 36 + 32 * 64 + 64];   // 17.7 KB
    if (blockIdx.x >= PB) {
        gemm_body<128, 64, true>(blockIdx.x - PB, X, W, gamma, var, Hs, n, lds);
        return;
    }
    // ---- partition branch: bin 4096 edges by dst>>8 ----
    int* lcnt  = (int*)lds;          // 196
    int* gbase = ((int*)lds) + 256;  // 196
    int t = threadIdx.x;
    int base = blockIdx.x * 4096;
    for (int i = t; i < NBUCK; i += 256) lcnt[i] = 0;
    __syncthreads();
    unsigned int val[16], pk[16];
#pragma unroll
    for (int i = 0; i < 16; ++i) {
        int e = base + i * 256 + t;
        if (e < nE) {
            unsigned s = (unsigned)src[e], d = (unsigned)dst[e];
            unsigned b = d >> 8;
            int r = atomicAdd(&lcnt[b], 1);
            val[i] = s | ((d & 255u) << 16);
            pk[i] = b | ((unsigned)r << 8);
        } else pk[i] = 0xffffffffu;
    }
    __syncthreads();
    for (int i = t; i < NBUCK; i += 256) gbase[i] = atomicAdd(&gcur[i], lcnt[i]);
    __syncthreads();
#pragma unroll
    for (int i = 0; i < 16; ++i) {
        if (pk[i] != 0xffffffffu) {
            unsigned b = pk[i] & 255u;
            unsigned p = (unsigned)gbase[b] + (pk[i] >> 8);
            if (p < PART_CAP) part[b * PART_CAP + p] = val[i];
        }
    }
}

// ---------------- dispatch 3: CSR build at 1024 threads/bucket ----------------
// (1024-wide proven r7: -6.5us vs 256-wide. Counting sort by (node, src-phase).)
__global__ __launch_bounds__(1024, 1)
void build_kernel(const unsigned int* __restrict__ part, const int* __restrict__ gcur,
                  int* __restrict__ rowptr, float* __restrict__ dinv,
                  unsigned short* __restrict__ csr, const float* __restrict__ Hs,
                  __half* __restrict__ Hh, int n) {
    __shared__ int buf[1024];          // scan scratch (reused)
    __shared__ int nc4[1024], cur4[1024];
    __shared__ float sdinv[256];
    __shared__ unsigned short csr_lds[PART_CAP];
    __shared__ int sh[2];              // sh[0]=off, sh[1]=ec
    int b = blockIdx.x, t = threadIdx.x;

    // bucket-offset scan over gcur (1024-wide; entries >= NBUCK are 0)
    int v = (t < NBUCK) ? gcur[t] : 0;
    int ex = lds_scan_excl<1024>(buf, t, v);
    if (t == b) { sh[0] = ex; sh[1] = v; }
    nc4[t] = 0;
    __syncthreads();
    int off = sh[0];
    int ec = sh[1] < PART_CAP ? sh[1] : PART_CAP;
    const unsigned int* pb = part + (size_t)b * PART_CAP;

    // histogram per (node, phase)
    for (int i = t; i < ec; i += 1024) {
        unsigned w = pb[i];
        atomicAdd(&nc4[((w >> 16) & 255u) * 4 + src_phase(w & 0xffffu)], 1);
    }
    __syncthreads();

    // per-node prefix (nodes owned by threads 0..255)
    int c = 0, c0 = 0, c1 = 0, c2 = 0;
    if (t < 256) {
        c0 = nc4[t * 4 + 0]; c1 = nc4[t * 4 + 1]; c2 = nc4[t * 4 + 2];
        c = c0 + c1 + c2 + nc4[t * 4 + 3];
    }
    int nx = lds_scan_excl<1024>(buf, t, c);
    if (t < 256) {
        cur4[t * 4 + 0] = nx;
        cur4[t * 4 + 1] = nx + c0;
        cur4[t * 4 + 2] = nx + c0 + c1;
        cur4[t * 4 + 3] = nx + c0 + c1 + c2;
        float dv = rsqrtf((float)c + 1.0f);   // +1 = self loop
        sdinv[t] = dv;
        int node = b * 256 + t;
        if (node < n) {
            rowptr[node] = off + nx;
            dinv[node] = dv;
        }
    }
    if (b == NBUCK - 1 && t == 0) rowptr[n] = off + ec;
    __syncthreads();

    // scatter: phase-grouped within each node's sublist
    for (int i = t; i < ec; i += 1024) {
        unsigned w = pb[i];
        unsigned nd = (w >> 16) & 255u;
        unsigned s = w & 0xffffu;
        int p = atomicAdd(&cur4[nd * 4 + src_phase(s)], 1);
        csr_lds[p] = (unsigned short)s;
    }
    __syncthreads();
    for (int i = t; i < ec; i += 1024) csr[off + i] = csr_lds[i];

    // convert this bucket's Hs rows to fp16 with dinv prefold
    const float4* H4 = (const float4*)(Hs + (size_t)b * 256 * 64);
    for (int i = t; i < 4096; i += 1024) {
        int nd = i >> 4;
        int nn = b * 256 + nd;
        if (nn < n) {
            float s = sdinv[nd];
            float4 x = H4[i];
            union { uint2 u; __half2 h[2]; } U;
            U.h[0] = __floats2half2_rn(x.x * s, x.y * s);
            U.h[1] = __floats2half2_rn(x.z * s, x.w * s);
            *(uint2*)&Hh[(size_t)nn * 64 + (i & 15) * 4] = U.u;
        }
    }
}

// ---------------- fused gather (fp16 table, BN+ReLU) + next-layer GEMM ----------------
// block = 32 nodes x 8 lanes; each lane owns 8 channels (16B fp16 loads).
// launch_bounds (256,5): 102-VGPR cap. The 8-deep unroll's live set (vv[8]=32 + sidx[8]
// + acc[8] + 8 in-flight 64-bit addrs + bases) is ~75-90 VGPR -- the prior (256,6)
// 85-VGPR cap sat exactly on it, risking scratch spills in the hot loop (r6's mega-kernel
// showed this failure mode at scale). 5 blocks/CU keeps LDS at 125 KB.
template <int MOUT, bool FOLD_NEXT>
__global__ __launch_bounds__(256, 5)
void gather_gemm_h(const __half* __restrict__ Hh, const int* __restrict__ rowptr,
                   const unsigned short* __restrict__ csr, const float* __restrict__ dinv,
                   const float* __restrict__ bb, const float* __restrict__ gamma,
                   const float* __restrict__ beta, const float* __restrict__ mean,
                   const float* __restrict__ var,
                   const float* __restrict__ Wn, const float* __restrict__ gn,
                   const float* __restrict__ vn, __half* __restrict__ Hout, int n) {
    __shared__ float zs[32 * 68];          // pad 68: conflict-free b128 broadcast per node
    __shared__ float Ws[64 * MOUT];
    int t = threadIdx.x;
    int nd = t >> 3, l = t & 7;
    int d = blockIdx.x * 32 + nd;
    int c8 = l * 8;
    // stage next-layer W (BN-fold if requested); barrier BEFORE the long gather phase
    for (int i = t; i < 64 * MOUT; i += 256) {
        float w = Wn[i];
        if (FOLD_NEXT) { int c = i % MOUT; w *= gn[c] * rsqrtf(vn[c] + BN_EPS); }
        Ws[i] = w;
    }
    __syncthreads();
    float acc[8] = {};
    float di = 0.f;
    int beg = 0, end = 0;
    if (d < n) {
        beg = rowptr[d]; end = rowptr[d + 1];
        di = dinv[d];
        union { uint4 u; __half2 h[4]; } S;
        S.u = *(const uint4*)&Hh[(size_t)d * 64 + c8];   // self loop (prescaled)
#pragma unroll
        for (int p = 0; p < 4; ++p) {
            float2 f = __half22float2(S.h[p]);
            acc[2 * p] += f.x; acc[2 * p + 1] += f.y;
        }
    }
    int e = beg;
    int head = (beg + 7) & ~7;             // align for uint4 index loads
    if (head > end) head = end;
    for (; e < head; ++e) {
        int s = csr[e];
        union { uint4 u; __half2 h[4]; } V;
        V.u = *(const uint4*)&Hh[(size_t)s * 64 + c8];
#pragma unroll
        for (int p = 0; p < 4; ++p) {
            float2 f = __half22float2(V.h[p]);
            acc[2 * p] += f.x; acc[2 * p + 1] += f.y;
        }
    }
    for (; e + 8 <= end; e += 8) {
        uint4 iv = *(const uint4*)&csr[e];   // 8 indices in one 16B load
        int sidx[8];
        sidx[0] = iv.x & 0xffff; sidx[1] = iv.x >> 16;
        sidx[2] = iv.y & 0xffff; sidx[3] = iv.y >> 16;
        sidx[4] = iv.z & 0xffff; sidx[5] = iv.z >> 16;
        sidx[6] = iv.w & 0xffff; sidx[7] = iv.w >> 16;
        uint4 vv[8];
#pragma unroll
        for (int q = 0; q < 8; ++q)
            vv[q] = *(const uint4*)&Hh[(size_t)sidx[q] * 64 + c8];
#pragma unroll
        for (int q = 0; q < 8; ++q) {
            union { uint4 u; __half2 h[4]; } V; V.u = vv[q];
#pragma unroll
            for (int p = 0; p < 4; ++p) {
                float2 f = __half22float2(V.h[p]);
                acc[2 * p] += f.x; acc[2 * p + 1] += f.y;
            }
        }
    }
    for (; e < end; ++e) {
        int s = csr[e];
        union { uint4 u; __half2 h[4]; } V;
        V.u = *(const uint4*)&Hh[(size_t)s * 64 + c8];
#pragma unroll
        for (int p = 0; p < 4; ++p) {
            float2 f = __half22float2(V.h[p]);
            acc[2 * p] += f.x; acc[2 * p + 1] += f.y;
        }
    }
    // BN bias + ReLU of current layer, write z tile to LDS (own wave's rows only)
    if (d < n) {
#pragma unroll
        for (int q = 0; q < 8; ++q) {
            int cc = c8 + q;
            float s0 = gamma[cc] * rsqrtf(var[cc] + BN_EPS);
            float bias = (bb[cc] - mean[cc]) * s0 + beta[cc];
            zs[nd * 68 + cc] = fmaxf(acc[q] * di + bias, 0.0f);
        }
    }
    // wave-local handoff: drain this wave's ds_writes; lockstep makes all 8 lanes' z visible.
    // sched_barrier(0) pins ordering against compiler hoisting (guide rule #18).
    asm volatile("s_waitcnt lgkmcnt(0)" ::: "memory");
    __builtin_amdgcn_sched_barrier(0);
    // ---- gemm phase: Hout[d, c8..c8+7] = fp16(dinv[d] * sum_k zs[nd][k] * Ws[k][c]) ----
    if (c8 < MOUT && d < n) {
        float o[8] = {};
        for (int k0 = 0; k0 < 64; k0 += 4) {
            float4 zq = *(const float4*)&zs[nd * 68 + k0];
#pragma unroll
            for (int j = 0; j < 4; ++j) {
                float zk = (&zq.x)[j];
                float4 w0 = *(const float4*)&Ws[(k0 + j) * MOUT + c8];
                float4 w1 = *(const float4*)&Ws[(k0 + j) * MOUT + c8 + 4];
                o[0] += zk * w0.x; o[1] += zk * w0.y; o[2] += zk * w0.z; o[3] += zk * w0.w;
                o[4] += zk * w1.x; o[5] += zk * w1.y; o[6] += zk * w1.z; o[7] += zk * w1.w;
            }
        }
        union { uint4 u; __half2 h[4]; } O;
#pragma unroll
        for (int p = 0; p < 4; ++p)
            O.h[p] = __floats2half2_rn(o[2 * p] * di, o[2 * p + 1] * di);
        *(uint4*)&Hout[(size_t)d * MOUT + c8] = O.u;
    }
}

// ---------------- final gather over fp16 40-ch rows; fp32 out ----------------
// block = 50 nodes x 5 lanes (250 active threads); lane owns 8 channels (16B loads).
// launch_bounds (256,6): 85-VGPR cap. Prior (256,8) capped at 64 VGPR with a ~60-70
// live set in the 8-deep unroll -- near-certain scratch spills. Occupancy 8->6 is cheap
// (no LDS; latency hiding still ample at 24 waves/CU).
__global__ __launch_bounds__(256, 6)
void gather_out_kernel(const __half* __restrict__ t3, const int* __restrict__ rowptr,
                       const unsigned short* __restrict__ csr, const float* __restrict__ dinv,
                       const float* __restrict__ bias, float* __restrict__ out, int n) {
    int t = threadIdx.x;
    if (t >= 250) return;
    int nd = t / 5, l = t % 5;
    int d = blockIdx.x * 50 + nd;
    if (d >= n) return;
    int c8 = l * 8;
    int beg = rowptr[d], end = rowptr[d + 1];
    float di = dinv[d];
    float acc[8];
    {
        union { uint4 u; __half2 h[4]; } S;
        S.u = *(const uint4*)&t3[(size_t)d * 40 + c8];
#pragma unroll
        for (int p = 0; p < 4; ++p) {
            float2 f = __half22float2(S.h[p]);
            acc[2 * p] = f.x; acc[2 * p + 1] = f.y;
        }
    }
    int e = beg;
    int head = (beg + 7) & ~7;
    if (head > end) head = end;
    for (; e < head; ++e) {
        int s = csr[e];
        union { uint4 u; __half2 h[4]; } V;
        V.u = *(const uint4*)&t3[(size_t)s * 40 + c8];
#pragma unroll
        for (int p = 0; p < 4; ++p) {
            float2 f = __half22float2(V.h[p]);
            acc[2 * p] += f.x; acc[2 * p + 1] += f.y;
        }
    }
    for (; e + 8 <= end; e += 8) {
        uint4 iv = *(const uint4*)&csr[e];
        int sidx[8];
        sidx[0] = iv.x & 0xffff; sidx[1] = iv.x >> 16;
        sidx[2] = iv.y & 0xffff; sidx[3] = iv.y >> 16;
        sidx[4] = iv.z & 0xffff; sidx[5] = iv.z >> 16;
        sidx[6] = iv.w & 0xffff; sidx[7] = iv.w >> 16;
        uint4 vv[8];
#pragma unroll
        for (int q = 0; q < 8; ++q)
            vv[q] = *(const uint4*)&t3[(size_t)sidx[q] * 40 + c8];
#pragma unroll
        for (int q = 0; q < 8; ++q) {
            union { uint4 u; __half2 h[4]; } V; V.u = vv[q];
#pragma unroll
            for (int p = 0; p < 4; ++p) {
                float2 f = __half22float2(V.h[p]);
                acc[2 * p] += f.x; acc[2 * p + 1] += f.y;
            }
        }
    }
    for (; e < end; ++e) {
        int s = csr[e];
        union { uint4 u; __half2 h[4]; } V;
        V.u = *(const uint4*)&t3[(size_t)s * 40 + c8];
#pragma unroll
        for (int p = 0; p < 4; ++p) {
            float2 f = __half22float2(V.h[p]);
            acc[2 * p] += f.x; acc[2 * p + 1] += f.y;
        }
    }
    float4 r0, r1;
    r0.x = acc[0] * di + bias[c8 + 0];
    r0.y = acc[1] * di + bias[c8 + 1];
    r0.z = acc[2] * di + bias[c8 + 2];
    r0.w = acc[3] * di + bias[c8 + 3];
    r1.x = acc[4] * di + bias[c8 + 4];
    r1.y = acc[5] * di + bias[c8 + 5];
    r1.z = acc[6] * di + bias[c8 + 6];
    r1.w = acc[7] * di + bias[c8 + 7];
    *(float4*)&out[(size_t)d * 40 + c8] = r0;
    *(float4*)&out[(size_t)d * 40 + c8 + 4] = r1;
}

extern "C" void kernel_launch(void* const* d_in, const int* in_sizes, int n_in,
                              void* d_out, int out_size, void* d_ws, size_t ws_size,
                              hipStream_t stream) {
    const float* x      = (const float*)d_in[0];
    const int*   ei     = (const int*)d_in[1];
    const float* W0     = (const float*)d_in[2];
    const float* b0     = (const float*)d_in[3];
    const float* gamma0 = (const float*)d_in[4];
    const float* beta0  = (const float*)d_in[5];
    const float* mean0  = (const float*)d_in[6];
    const float* var0   = (const float*)d_in[7];
    const float* W1     = (const float*)d_in[8];
    const float* b1     = (const float*)d_in[9];
    const float* gamma1 = (const float*)d_in[10];
    const float* beta1  = (const float*)d_in[11];
    const float* mean1  = (const float*)d_in[12];
    const float* var1   = (const float*)d_in[13];
    const float* W2     = (const float*)d_in[14];
    const float* b2     = (const float*)d_in[15];
    float* out = (float*)d_out;

    const int* srcp = ei;
    const int* dstp = ei + N_EDGES;
    const int N = N_NODES, E = N_EDGES;

    // workspace carve-up (bytes, 16B-aligned). Total footprint 27.6 MB.
    char* ws = (char*)d_ws;
    int*            gcur   = (int*)(ws + 0);          // 784 B
    int*            rowptr = (int*)(ws + 1024);       // 200004
    float*          dinv   = (float*)(ws + 202240);   // 200000
    unsigned short* csr    = (unsigned short*)(ws + 402688);   // 1.6 MB
    float*          Hs     = (float*)(ws + 2002944);  // 12.8 MB fp32 gemm0 out (dead after d3)
    __half*         bufh   = (__half*)(ws + 2002944); // 6.4 MB, aliases Hs (written in d4)
    __half*         t3h    = (__half*)(ws + 8402944); // 4.0 MB (written in d5)
    unsigned int*   part   = (unsigned int*)(ws + 14802944);   // 4.7 MB (dead after d3)
    __half*         Hh     = (__half*)(ws + 21202944);         // 6.4 MB fp16 prescaled table

    hipMemsetAsync(gcur, 0, NBUCK * sizeof(int), stream);

    // d2: partition (blocks 0..195) + gemm0 (BN0-folded, 64-row tiles) in one dispatch
    fused_gemm0_partition_kernel<<<PB + GB, 256, 0, stream>>>(
        x, W0, gamma0, var0, Hs, N, srcp, dstp, gcur, part, E);

    // d3: CSR build (1024 thr/bucket) + rowptr + dinv + fp16 prefolded table Hh
    build_kernel<<<NBUCK, 1024, 0, stream>>>(part, gcur, rowptr, dinv, csr, Hs, Hh, N);

    // d4: gather layer0 (fp16 rows, BN0 bias+relu) + gemm1 (BN1-scale folded) -> bufh (fp16)
    gather_gemm_h<64, true><<<(N + 31) / 32, 256, 0, stream>>>(
        Hh, rowptr, csr, dinv, b0, gamma0, beta0, mean0, var0,
        W1, gamma1, var1, bufh, N);

    // d5: gather layer1 (fp16 rows, BN1 bias+relu) + gemm2 (raw W2) -> t3h (fp16, 40ch)
    gather_gemm_h<40, false><<<(N + 31) / 32, 256, 0, stream>>>(
        bufh, rowptr, csr, dinv, b1, gamma1, beta1, mean1, var1,
        W2, nullptr, nullptr, t3h, N);

    // d6: final gather over t3h + b2 -> fp32 out
    gather_out_kernel<<<N / 50, 256, 0, stream>>>(t3h, rowptr, csr, dinv, b2, out, N);
}

// Round 11
// 184.562 us; speedup vs baseline: 5.1164x; 1.1357x over previous
//
#include <hip/hip_runtime.h>
#include <hip/hip_fp16.h>

#define N_NODES 50000
#define N_EDGES 800000
#define BN_EPS 1e-5f

#define NBUCK 196        // ceil(50000/256) buckets of 256 nodes
#define PART_CAP 6016    // per-bucket raw capacity; mean 4082, sd 64 -> 30 sigma margin
#define BUCK_STRIDE 1800 // per-bucket pad allowance: 256 nodes * 7 max pad, 8-aligned, +slack
#define CSR_LDS_CAP 7808 // PART_CAP + 256*7
#define PAD_IDX 50000    // dummy src index -> zero row appended to each gather table
#define PB 196           // partition blocks (ceil(800000/4096))
#define GB 782           // gemm0 blocks (ceil(50000/64), 64-row tiles)

// exclusive WIDTH-thread scan in LDS; s[] is scratch (WIDTH ints). All WIDTH threads call.
// After return, s[WIDTH-1] holds the inclusive total (valid until s is rewritten).
template <int WIDTH>
__device__ __forceinline__ int lds_scan_excl(int* s, int t, int v) {
    s[t] = v;
    __syncthreads();
    for (int off = 1; off < WIDTH; off <<= 1) {
        int x = (t >= off) ? s[t - off] : 0;
        __syncthreads();
        s[t] += x;
        __syncthreads();
    }
    return s[t] - v;
}

// phase of a source node id (4 ranges of 12500); exact floor(s/12500) for s<50000
__device__ __forceinline__ unsigned src_phase(unsigned s) {
    return (s * 42950u) >> 29;
}

// ---------------- GEMM body: Hs[r,M] = X[r,K] @ (W .* foldscale[c]) ----------------
// 64-row tile; 256 threads = 16x16, each 4x4; K chunked by 32. (proven shape: 978-block
// grid keeps ~4 blocks/CU. 8x8/256-row variant: 76us @ 8% VALUBusy, parallelism collapse.
// r6 mega-fusion: regalloc collapse -> 40 VGPR + 250MB scratch spill, 944us. Keep split.)
template <int K, int M, bool FOLD>
__device__ __forceinline__ void gemm_body(int bid, const float* __restrict__ X,
                                          const float* __restrict__ W,
                                          const float* __restrict__ gamma,
                                          const float* __restrict__ var,
                                          float* __restrict__ Hs, int n, float* lds) {
    constexpr int KC = 32;
    float* Xs = lds;                    // 64 x 36
    float* Ws = lds + 64 * 36;          // 32 x M
    float* bns = lds + 64 * 36 + 32 * M; // M bn scales
    int tid = threadIdx.x;
    int tx = tid & 15, ty = tid >> 4;
    int row0 = bid * 64;
    if (FOLD && tid < M) bns[tid] = gamma[tid] * rsqrtf(var[tid] + BN_EPS);
    __syncthreads();
    float acc[4][4] = {};
    for (int k0 = 0; k0 < K; k0 += KC) {
#pragma unroll
        for (int it = 0; it < 2; ++it) {
            int fi = tid + it * 256;            // 512 float4s
            int r = fi >> 3, q = fi & 7;
            int row = row0 + r;
            float4 v = make_float4(0.f, 0.f, 0.f, 0.f);
            if (row < n) v = *(const float4*)&X[(size_t)row * K + k0 + q * 4];
            *(float4*)&Xs[r * 36 + q * 4] = v;
        }
#pragma unroll
        for (int it = 0; it < 2; ++it) {
            int fi = tid + it * 256;            // 512 float4s (32*M/4 with M=64)
            int kk = fi >> 4, cw = (fi & 15) * 4;
            float4 w = *(const float4*)&W[(size_t)(k0 + kk) * M + cw];
            if (FOLD) { w.x *= bns[cw]; w.y *= bns[cw + 1]; w.z *= bns[cw + 2]; w.w *= bns[cw + 3]; }
            *(float4*)&Ws[kk * M + cw] = w;
        }
        __syncthreads();
#pragma unroll 8
        for (int kk = 0; kk < KC; ++kk) {
            float4 bv = *(float4*)&Ws[kk * M + tx * 4];
#pragma unroll
            for (int j = 0; j < 4; ++j) {
                float a = Xs[(ty * 4 + j) * 36 + kk];
                acc[j][0] += a * bv.x;
                acc[j][1] += a * bv.y;
                acc[j][2] += a * bv.z;
                acc[j][3] += a * bv.w;
            }
        }
        __syncthreads();
    }
#pragma unroll
    for (int j = 0; j < 4; ++j) {
        int r = row0 + ty * 4 + j;
        if (r < n) {
            float4 v = make_float4(acc[j][0], acc[j][1], acc[j][2], acc[j][3]);
            *(float4*)&Hs[(size_t)r * M + tx * 4] = v;
        }
    }
}

// ---------------- dispatch 2: partition blocks first, then gemm0 blocks ----------------
__global__ __launch_bounds__(256, 4)
void fused_gemm0_partition_kernel(const float* __restrict__ X, const float* __restrict__ W,
                                  const float* __restrict__ gamma, const float* __restrict__ var,
                                  float* __restrict__ Hs, int n,
                                  const int* __restrict__ src, const int* __restrict__ dst,
                                  int* __restrict__ gcur, unsigned int* __restrict__ part,
                                  int nE) {
    __shared__ float lds[64 * 36 + 32 * 64 + 64];   // 17.7 KB
    if (blockIdx.x >= PB) {
        gemm_body<128, 64, true>(blockIdx.x - PB, X, W, gamma, var, Hs, n, lds);
        return;
    }
    // ---- partition branch: bin 4096 edges by dst>>8 ----
    int* lcnt  = (int*)lds;          // 196
    int* gbase = ((int*)lds) + 256;  // 196
    int t = threadIdx.x;
    int base = blockIdx.x * 4096;
    for (int i = t; i < NBUCK; i += 256) lcnt[i] = 0;
    __syncthreads();
    unsigned int val[16], pk[16];
#pragma unroll
    for (int i = 0; i < 16; ++i) {
        int e = base + i * 256 + t;
        if (e < nE) {
            unsigned s = (unsigned)src[e], d = (unsigned)dst[e];
            unsigned b = d >> 8;
            int r = atomicAdd(&lcnt[b], 1);
            val[i] = s | ((d & 255u) << 16);
            pk[i] = b | ((unsigned)r << 8);
        } else pk[i] = 0xffffffffu;
    }
    __syncthreads();
    for (int i = t; i < NBUCK; i += 256) gbase[i] = atomicAdd(&gcur[i], lcnt[i]);
    __syncthreads();
#pragma unroll
    for (int i = 0; i < 16; ++i) {
        if (pk[i] != 0xffffffffu) {
            unsigned b = pk[i] & 255u;
            unsigned p = (unsigned)gbase[b] + (pk[i] >> 8);
            if (p < PART_CAP) part[b * PART_CAP + p] = val[i];
        }
    }
}

// ---------------- dispatch 3: CSR build, 8-PADDED lists + dinv + fp16 table ----------------
// Each node's list is padded to a multiple of 8 with PAD_IDX (-> zero row), so the gather
// loop is a single branch-free 8-deep batch loop at uniform MLP=8 (r10 showed gathers are
// latency*MLP bound; scalar tails ran at MLP~1-2). Starts are 8-aligned -> aligned uint4
// csr loads. rowptr is uint2{beg,end}. 1024 thr/bucket (r7: -6.5us vs 256).
__global__ __launch_bounds__(1024, 1)
void build_kernel(const unsigned int* __restrict__ part, const int* __restrict__ gcur,
                  uint2* __restrict__ rowptr, float* __restrict__ dinv,
                  unsigned short* __restrict__ csr, const float* __restrict__ Hs,
                  __half* __restrict__ Hh, int n) {
    __shared__ int buf[1024];          // scan scratch (reused)
    __shared__ int nc4[1024], cur4[1024];
    __shared__ float sdinv[256];
    __shared__ unsigned short csr_lds[CSR_LDS_CAP];
    __shared__ int sh[2];              // sh[0]=padded base, sh[1]=raw ec
    int b = blockIdx.x, t = threadIdx.x;

    // zero row of Hh (once, block 0): 64 halves = 8 uint4
    if (b == 0 && t < 8) ((uint4*)(Hh + (size_t)PAD_IDX * 64))[t] = make_uint4(0, 0, 0, 0);

    // bucket-offset scan over gcur (raw counts); padded base = align8(raw base) + b*BUCK_STRIDE
    int v = (t < NBUCK) ? gcur[t] : 0;
    int ex = lds_scan_excl<1024>(buf, t, v);
    if (t == b) { sh[0] = ((ex + 7) & ~7) + b * BUCK_STRIDE; sh[1] = v; }
    nc4[t] = 0;
    __syncthreads();
    int base = sh[0];
    int ec = sh[1] < PART_CAP ? sh[1] : PART_CAP;
    const unsigned int* pb = part + (size_t)b * PART_CAP;

    // histogram per (node, phase)
    for (int i = t; i < ec; i += 1024) {
        unsigned w = pb[i];
        atomicAdd(&nc4[((w >> 16) & 255u) * 4 + src_phase(w & 0xffffu)], 1);
    }
    __syncthreads();

    // per-node prefix over PADDED counts (nodes owned by threads 0..255)
    int c = 0, c0 = 0, c1 = 0, c2 = 0, cp = 0;
    if (t < 256) {
        c0 = nc4[t * 4 + 0]; c1 = nc4[t * 4 + 1]; c2 = nc4[t * 4 + 2];
        c = c0 + c1 + c2 + nc4[t * 4 + 3];
        cp = (c + 7) & ~7;
    }
    int nx = lds_scan_excl<1024>(buf, t, cp);
    int ptot = buf[1023];              // padded total of this bucket (valid post-scan)
    if (t < 256) {
        cur4[t * 4 + 0] = nx;
        cur4[t * 4 + 1] = nx + c0;
        cur4[t * 4 + 2] = nx + c0 + c1;
        cur4[t * 4 + 3] = nx + c0 + c1 + c2;
        float dv = rsqrtf((float)c + 1.0f);   // +1 = self loop (raw degree)
        sdinv[t] = dv;
        int node = b * 256 + t;
        if (node < n) {
            rowptr[node] = make_uint2((unsigned)(base + nx), (unsigned)(base + nx + cp));
            dinv[node] = dv;
        }
    }
    __syncthreads();

    // scatter real edges (phase-grouped within node), then fill pad slots with PAD_IDX
    for (int i = t; i < ec; i += 1024) {
        unsigned w = pb[i];
        unsigned nd = (w >> 16) & 255u;
        unsigned s = w & 0xffffu;
        int p = atomicAdd(&cur4[nd * 4 + src_phase(s)], 1);
        csr_lds[p] = (unsigned short)s;
    }
    if (t < 256) {
        for (int i = nx + c; i < nx + cp; ++i) csr_lds[i] = (unsigned short)PAD_IDX;
    }
    __syncthreads();
    for (int i = t; i < ptot; i += 1024) csr[base + i] = csr_lds[i];

    // convert this bucket's Hs rows to fp16 with dinv prefold
    const float4* H4 = (const float4*)(Hs + (size_t)b * 256 * 64);
    for (int i = t; i < 4096; i += 1024) {
        int nd = i >> 4;
        int nn = b * 256 + nd;
        if (nn < n) {
            float s = sdinv[nd];
            float4 x = H4[i];
            union { uint2 u; __half2 h[2]; } U;
            U.h[0] = __floats2half2_rn(x.x * s, x.y * s);
            U.h[1] = __floats2half2_rn(x.z * s, x.w * s);
            *(uint2*)&Hh[(size_t)nn * 64 + (i & 15) * 4] = U.u;
        }
    }
}

// ---------------- fused gather (fp16 table, BN+ReLU) + next-layer GEMM ----------------
// block = 32 nodes x 8 lanes; lane owns 8 channels (16B fp16 loads). Pure 8-deep batch
// loop (lists 8-padded; PAD_IDX rows are zero). launch_bounds (256,5): 102-VGPR cap --
// r10 proved the (256,6) 85-cap strangled load MLP (-14.5us when relaxed).
template <int MOUT, bool FOLD_NEXT>
__global__ __launch_bounds__(256, 5)
void gather_gemm_h(const __half* __restrict__ Hh, const uint2* __restrict__ rowptr,
                   const unsigned short* __restrict__ csr, const float* __restrict__ dinv,
                   const float* __restrict__ bb, const float* __restrict__ gamma,
                   const float* __restrict__ beta, const float* __restrict__ mean,
                   const float* __restrict__ var,
                   const float* __restrict__ Wn, const float* __restrict__ gn,
                   const float* __restrict__ vn, __half* __restrict__ Hout, int n) {
    __shared__ float zs[32 * 68];          // pad 68: conflict-free b128 broadcast per node
    __shared__ float Ws[64 * MOUT];
    int t = threadIdx.x;
    int nd = t >> 3, l = t & 7;
    int d = blockIdx.x * 32 + nd;
    int c8 = l * 8;
    // zero row of Hout (once): pad rows of the NEXT gather read this
    if (blockIdx.x == 0 && t < MOUT) Hout[(size_t)PAD_IDX * MOUT + t] = __float2half(0.f);
    // stage next-layer W (BN-fold if requested); barrier BEFORE the long gather phase
    for (int i = t; i < 64 * MOUT; i += 256) {
        float w = Wn[i];
        if (FOLD_NEXT) { int c = i % MOUT; w *= gn[c] * rsqrtf(vn[c] + BN_EPS); }
        Ws[i] = w;
    }
    __syncthreads();
    float acc[8] = {};
    float di = 0.f;
    int e = 0, end = 0;
    if (d < n) {
        uint2 rp = rowptr[d];
        e = (int)rp.x; end = (int)rp.y;
        di = dinv[d];
        union { uint4 u; __half2 h[4]; } S;
        S.u = *(const uint4*)&Hh[(size_t)d * 64 + c8];   // self loop (prescaled)
#pragma unroll
        for (int p = 0; p < 4; ++p) {
            float2 f = __half22float2(S.h[p]);
            acc[2 * p] += f.x; acc[2 * p + 1] += f.y;
        }
    }
    for (; e < end; e += 8) {
        uint4 iv = *(const uint4*)&csr[e];   // 8 indices in one aligned 16B load
        int sidx[8];
        sidx[0] = iv.x & 0xffff; sidx[1] = iv.x >> 16;
        sidx[2] = iv.y & 0xffff; sidx[3] = iv.y >> 16;
        sidx[4] = iv.z & 0xffff; sidx[5] = iv.z >> 16;
        sidx[6] = iv.w & 0xffff; sidx[7] = iv.w >> 16;
        uint4 vv[8];
#pragma unroll
        for (int q = 0; q < 8; ++q)
            vv[q] = *(const uint4*)&Hh[(size_t)sidx[q] * 64 + c8];
#pragma unroll
        for (int q = 0; q < 8; ++q) {
            union { uint4 u; __half2 h[4]; } V; V.u = vv[q];
#pragma unroll
            for (int p = 0; p < 4; ++p) {
                float2 f = __half22float2(V.h[p]);
                acc[2 * p] += f.x; acc[2 * p + 1] += f.y;
            }
        }
    }
    // BN bias + ReLU of current layer, write z tile to LDS (own wave's rows only)
    if (d < n) {
#pragma unroll
        for (int q = 0; q < 8; ++q) {
            int cc = c8 + q;
            float s0 = gamma[cc] * rsqrtf(var[cc] + BN_EPS);
            float bias = (bb[cc] - mean[cc]) * s0 + beta[cc];
            zs[nd * 68 + cc] = fmaxf(acc[q] * di + bias, 0.0f);
        }
    }
    // wave-local handoff (gemm reads only own wave's zs rows): drain ds_writes; pin order.
    asm volatile("s_waitcnt lgkmcnt(0)" ::: "memory");
    __builtin_amdgcn_sched_barrier(0);
    // ---- gemm phase: Hout[d, c8..c8+7] = fp16(dinv[d] * sum_k zs[nd][k] * Ws[k][c]) ----
    if (c8 < MOUT && d < n) {
        float o[8] = {};
        for (int k0 = 0; k0 < 64; k0 += 4) {
            float4 zq = *(const float4*)&zs[nd * 68 + k0];
#pragma unroll
            for (int j = 0; j < 4; ++j) {
                float zk = (&zq.x)[j];
                float4 w0 = *(const float4*)&Ws[(k0 + j) * MOUT + c8];
                float4 w1 = *(const float4*)&Ws[(k0 + j) * MOUT + c8 + 4];
                o[0] += zk * w0.x; o[1] += zk * w0.y; o[2] += zk * w0.z; o[3] += zk * w0.w;
                o[4] += zk * w1.x; o[5] += zk * w1.y; o[6] += zk * w1.z; o[7] += zk * w1.w;
            }
        }
        union { uint4 u; __half2 h[4]; } O;
#pragma unroll
        for (int p = 0; p < 4; ++p)
            O.h[p] = __floats2half2_rn(o[2 * p] * di, o[2 * p + 1] * di);
        *(uint4*)&Hout[(size_t)d * MOUT + c8] = O.u;
    }
}

// ---------------- final gather over fp16 40-ch rows; fp32 out ----------------
// block = 50 nodes x 5 lanes (250 active); lane owns 8 channels. Pure 8-deep batches.
// launch_bounds (256,6): 85-VGPR cap (r10: the (256,8) 64-cap spilled/serialized loads).
__global__ __launch_bounds__(256, 6)
void gather_out_kernel(const __half* __restrict__ t3, const uint2* __restrict__ rowptr,
                       const unsigned short* __restrict__ csr, const float* __restrict__ dinv,
                       const float* __restrict__ bias, float* __restrict__ out, int n) {
    int t = threadIdx.x;
    if (t >= 250) return;
    int nd = t / 5, l = t % 5;
    int d = blockIdx.x * 50 + nd;
    if (d >= n) return;
    int c8 = l * 8;
    uint2 rp = rowptr[d];
    int e = (int)rp.x, end = (int)rp.y;
    float di = dinv[d];
    float acc[8];
    {
        union { uint4 u; __half2 h[4]; } S;
        S.u = *(const uint4*)&t3[(size_t)d * 40 + c8];
#pragma unroll
        for (int p = 0; p < 4; ++p) {
            float2 f = __half22float2(S.h[p]);
            acc[2 * p] = f.x; acc[2 * p + 1] = f.y;
        }
    }
    for (; e < end; e += 8) {
        uint4 iv = *(const uint4*)&csr[e];
        int sidx[8];
        sidx[0] = iv.x & 0xffff; sidx[1] = iv.x >> 16;
        sidx[2] = iv.y & 0xffff; sidx[3] = iv.y >> 16;
        sidx[4] = iv.z & 0xffff; sidx[5] = iv.z >> 16;
        sidx[6] = iv.w & 0xffff; sidx[7] = iv.w >> 16;
        uint4 vv[8];
#pragma unroll
        for (int q = 0; q < 8; ++q)
            vv[q] = *(const uint4*)&t3[(size_t)sidx[q] * 40 + c8];
#pragma unroll
        for (int q = 0; q < 8; ++q) {
            union { uint4 u; __half2 h[4]; } V; V.u = vv[q];
#pragma unroll
            for (int p = 0; p < 4; ++p) {
                float2 f = __half22float2(V.h[p]);
                acc[2 * p] += f.x; acc[2 * p + 1] += f.y;
            }
        }
    }
    float4 r0, r1;
    r0.x = acc[0] * di + bias[c8 + 0];
    r0.y = acc[1] * di + bias[c8 + 1];
    r0.z = acc[2] * di + bias[c8 + 2];
    r0.w = acc[3] * di + bias[c8 + 3];
    r1.x = acc[4] * di + bias[c8 + 4];
    r1.y = acc[5] * di + bias[c8 + 5];
    r1.z = acc[6] * di + bias[c8 + 6];
    r1.w = acc[7] * di + bias[c8 + 7];
    *(float4*)&out[(size_t)d * 40 + c8] = r0;
    *(float4*)&out[(size_t)d * 40 + c8 + 4] = r1;
}

extern "C" void kernel_launch(void* const* d_in, const int* in_sizes, int n_in,
                              void* d_out, int out_size, void* d_ws, size_t ws_size,
                              hipStream_t stream) {
    const float* x      = (const float*)d_in[0];
    const int*   ei     = (const int*)d_in[1];
    const float* W0     = (const float*)d_in[2];
    const float* b0     = (const float*)d_in[3];
    const float* gamma0 = (const float*)d_in[4];
    const float* beta0  = (const float*)d_in[5];
    const float* mean0  = (const float*)d_in[6];
    const float* var0   = (const float*)d_in[7];
    const float* W1     = (const float*)d_in[8];
    const float* b1     = (const float*)d_in[9];
    const float* gamma1 = (const float*)d_in[10];
    const float* beta1  = (const float*)d_in[11];
    const float* mean1  = (const float*)d_in[12];
    const float* var1   = (const float*)d_in[13];
    const float* W2     = (const float*)d_in[14];
    const float* b2     = (const float*)d_in[15];
    float* out = (float*)d_out;

    const int* srcp = ei;
    const int* dstp = ei + N_EDGES;
    const int N = N_NODES, E = N_EDGES;

    // workspace carve-up (bytes, 128-aligned). Total 26.9 MB (27.6 proven OK earlier).
    char* ws = (char*)d_ws;
    int*            gcur   = (int*)(ws + 0);            // 784 B
    uint2*          rowptr = (uint2*)(ws + 1024);       // 400 KB (beg,end per node)
    float*          dinv   = (float*)(ws + 401152);     // 200 KB
    unsigned short* csr    = (unsigned short*)(ws + 601344);   // 2.3 MB (8-padded lists)
    float*          Hs     = (float*)(ws + 2960896);    // 12.8 MB fp32 gemm0 out (dead after d3)
    __half*         bufh   = (__half*)(ws + 2960896);   // 6.4 MB+row, aliases Hs (written d4)
    __half*         t3h    = (__half*)(ws + 9361152);   // 4.0 MB+row (written d5)
    unsigned int*   part   = (unsigned int*)(ws + 15761152);   // 4.7 MB (dead after d3)
    __half*         Hh     = (__half*)(ws + 20477952);  // 6.4 MB+row fp16 prescaled table

    hipMemsetAsync(gcur, 0, NBUCK * sizeof(int), stream);

    // d2: partition (blocks 0..195) + gemm0 (BN0-folded, 64-row tiles) in one dispatch
    fused_gemm0_partition_kernel<<<PB + GB, 256, 0, stream>>>(
        x, W0, gamma0, var0, Hs, N, srcp, dstp, gcur, part, E);

    // d3: CSR build (8-padded, zero-row pads) + rowptr(beg,end) + dinv + fp16 table Hh
    build_kernel<<<NBUCK, 1024, 0, stream>>>(part, gcur, rowptr, dinv, csr, Hs, Hh, N);

    // d4: gather layer0 (fp16 rows, BN0 bias+relu) + gemm1 (BN1-scale folded) -> bufh (fp16)
    gather_gemm_h<64, true><<<(N + 31) / 32, 256, 0, stream>>>(
        Hh, rowptr, csr, dinv, b0, gamma0, beta0, mean0, var0,
        W1, gamma1, var1, bufh, N);

    // d5: gather layer1 (fp16 rows, BN1 bias+relu) + gemm2 (raw W2) -> t3h (fp16, 40ch)
    gather_gemm_h<40, false><<<(N + 31) / 32, 256, 0, stream>>>(
        bufh, rowptr, csr, dinv, b1, gamma1, beta1, mean1, var1,
        W2, nullptr, nullptr, t3h, N);

    // d6: final gather over t3h + b2 -> fp32 out
    gather_out_kernel<<<N / 50, 256, 0, stream>>>(t3h, rowptr, csr, dinv, b2, out, N);
}